// Round 10
// baseline (424.807 us; speedup 1.0000x reference)
//
#include <hip/hip_runtime.h>
#include <hip/hip_bf16.h>

// ---------------------------------------------------------------------------
// FieldPredictionNetwork. R15 (2nd submit — R9 bench was an MI355X container
// failure; kernel never ran. Deadlock audit clean: uniform barriers, exact
// lgkm/vm ledgers). R14 post-mortem = mid-barrier removal NULL (52.2us,
// MfmaUtil 25.5% — identical to R12). All coarse schedule variants sit at
// ~3900 cy/tile = the documented 2-phase ceiling. The proven lever
// (m196->m198, +28-41%) is the FINE per-phase interleave: small
// {ds_read subtile | stage -> barrier -> lgkm0 -> setprio MFMA burst ->
// barrier} phases. Port that onto the twice-verified 3-buffer ring:
// 4 phases/K-tile, one C-quadrant each (8 MFMA), frag reuse across phases
// (P1 A01+B01, P2 A23, P3 B23, P4 A01 reload), 2 DMA issues in P1-P3.
// Boundary ledger byte-identical to R12/R14 (lgkm0; vmcnt(6|0); barrier).
// conv_all fusion reverted (isolate GEMM delta). All else frozen at R13.
// ---------------------------------------------------------------------------

#define PI2F 6.28318530717958647692f

typedef __attribute__((ext_vector_type(8))) short short8;
typedef __attribute__((ext_vector_type(4))) float f32x4;

__device__ __forceinline__ unsigned short f2bf(float f) {
  unsigned int u = __float_as_uint(f);
  u += 0x7fff + ((u >> 16) & 1);          // RN-even
  return (unsigned short)(u >> 16);
}
__device__ __forceinline__ unsigned int pack_bf16x2(float a, float b) {
  return (unsigned int)f2bf(a) | ((unsigned int)f2bf(b) << 16);
}

// async 16B global->LDS DMA; lds dest must be wave-uniform (HW adds lane*16)
__device__ __forceinline__ void gl2lds16(const void* gptr, const void* lptr) {
  __builtin_amdgcn_global_load_lds(
      (const __attribute__((address_space(1))) unsigned int*)(unsigned long long)gptr,
      (__attribute__((address_space(3))) unsigned int*)(unsigned int)(unsigned long long)lptr,
      16, 0, 0);
}

// ---------------------------------------------------------------------------
// f32 -> bf16 pack (4 elems/thread)
// ---------------------------------------------------------------------------
__global__ __launch_bounds__(256) void f32_to_bf16_k(
    const float* __restrict__ src, unsigned short* __restrict__ dst, int n4)
{
  int i = blockIdx.x * 256 + threadIdx.x;
  if (i < n4) {
    float4 v = ((const float4*)src)[i];
    uint2 p;
    p.x = pack_bf16x2(v.x, v.y);
    p.y = pack_bf16x2(v.z, v.w);
    ((uint2*)dst)[i] = p;
  }
}

// ---------------------------------------------------------------------------
// R15 pipelined GEMM: C = relu(A @ Bw^T + bias). A [M,K] bf16, Bw [N,K] bf16.
// BM=128, BN=256, BK=64. 3-buffer LDS ring (144KB), counted vmcnt, 8 waves.
// 4 fine phases per K-tile: each = {quadrant frag ds_reads; 2 DMA issues;
// s_barrier; lgkmcnt(0); setprio(1); 8 MFMA; setprio(0); s_barrier}.
// 1D grid, nwg = (M/128)*(N/256), nwg % 8 == 0 required (XCD swizzle).
// ---------------------------------------------------------------------------
template<int NBLOG, typename OUT>
__global__ __launch_bounds__(512, 1) void gemm_pipe(
    const unsigned short* __restrict__ A, const unsigned short* __restrict__ Bw,
    const float* __restrict__ bias, OUT* __restrict__ C, int N, int K)
{
  constexpr int BM = 128, BN = 256, BK = 64;
  constexpr int ASZ = BM * BK;            // 8192 elems = 16 KB
  constexpr int BSZ = BN * BK;            // 16384 elems = 32 KB
  constexpr int BUF = ASZ + BSZ;          // 48 KB
  __shared__ __align__(16) unsigned short lds[3 * BUF];   // 144 KB

  // T1: bijective XCD swizzle (nwg multiple of 8) -> contiguous chunk per XCD
  const int nwg = gridDim.x;
  const int cpx = nwg >> 3;
  const int orig = blockIdx.x;
  const int wg = (orig & 7) * cpx + (orig >> 3);
  const int mb = wg >> NBLOG;
  const int nb = wg & ((1 << NBLOG) - 1);
  const size_t m0 = (size_t)mb * BM;
  const size_t n0 = (size_t)nb * BN;

  const int tid = threadIdx.x;
  const int lane = tid & 63;
  const int wv = tid >> 6;
  const int q = lane >> 4, lr = lane & 15;
  const int x7 = lr & 7;
  const int wm = (wv >> 2) * 64;          // 2 M-positions
  const int wn = (wv & 3) * 64;           // 4 N-positions
  f32x4 acc[4][4] = {};

  // stage 2 of this wave's 6 DMA instrs for one k-tile into ring buffer r.
  // instr id e = wv*6 + s0 + u; e<16 -> A instr e (rows 8e..8e+8), else B e-16.
  auto STAGE_PAIR = [&](int r, int kk, int s0) {
    unsigned short* dA = lds + r * BUF;
    #pragma unroll
    for (int u = 0; u < 2; ++u) {
      int e = wv * 6 + s0 + u;
      int isA = (e < 16) ? 1 : 0;
      int e2 = isA ? e : e - 16;
      int pc = e2 * 64 + lane;
      int row = pc >> 3, col = pc & 7;
      int lc = col ^ (row & 7);
      const unsigned short* src = isA ? A : Bw;
      size_t rb = isA ? m0 : n0;
      unsigned short* dst = dA + (isA ? 0 : ASZ) + e2 * 512;
      gl2lds16(src + (rb + row) * (size_t)K + kk + lc * 8, dst);
    }
  };

  const int nt = K / BK;                  // 8 or 16 here
  // prologue: tiles 0,1 -> bufs 0,1 (12 loads/wave); wait oldest 6 (tile 0)
  STAGE_PAIR(0, 0, 0); STAGE_PAIR(0, 0, 2); STAGE_PAIR(0, 0, 4);
  STAGE_PAIR(1, BK, 0); STAGE_PAIR(1, BK, 2); STAGE_PAIR(1, BK, 4);
  asm volatile("s_waitcnt vmcnt(6)" ::: "memory");
  __builtin_amdgcn_s_barrier();

  int r0 = 0;
  for (int t = 0; t < nt; ++t) {
    const unsigned short* sA = lds + r0 * BUF;
    const unsigned short* sB = sA + ASZ;
    const bool st = (t + 2) < nt;
    const int r2 = (r0 >= 1) ? (r0 - 1) : 2;    // (t+2)%3
    const int kk2 = (t + 2) * BK;

    short8 a0[2][2], a1[2][2], b0[2][2], b1[2][2];

    // ---- P1: quadrant (i=0..1, j=0..1). Load A01 + B01; 2 DMA.
    #pragma unroll
    for (int i = 0; i < 2; ++i)
      #pragma unroll
      for (int t2 = 0; t2 < 2; ++t2)
        a0[i][t2] = *(const short8*)(sA + (wm + i * 16 + lr) * 64 + (((t2 << 2) | q) ^ x7) * 8);
    #pragma unroll
    for (int j = 0; j < 2; ++j)
      #pragma unroll
      for (int t2 = 0; t2 < 2; ++t2)
        b0[j][t2] = *(const short8*)(sB + (wn + j * 16 + lr) * 64 + (((t2 << 2) | q) ^ x7) * 8);
    if (st) STAGE_PAIR(r2, kk2, 0);
    __builtin_amdgcn_s_barrier();
    asm volatile("s_waitcnt lgkmcnt(0)" ::: "memory");
    __builtin_amdgcn_s_setprio(1);
    #pragma unroll
    for (int i = 0; i < 2; ++i)
      #pragma unroll
      for (int j = 0; j < 2; ++j)
        #pragma unroll
        for (int t2 = 0; t2 < 2; ++t2)
          acc[i][j] = __builtin_amdgcn_mfma_f32_16x16x32_bf16(a0[i][t2], b0[j][t2], acc[i][j], 0, 0, 0);
    __builtin_amdgcn_s_setprio(0);
    __builtin_amdgcn_s_barrier();

    // ---- P2: quadrant (i=2..3, j=0..1). Load A23; reuse B01; 2 DMA.
    #pragma unroll
    for (int i = 0; i < 2; ++i)
      #pragma unroll
      for (int t2 = 0; t2 < 2; ++t2)
        a1[i][t2] = *(const short8*)(sA + (wm + (i + 2) * 16 + lr) * 64 + (((t2 << 2) | q) ^ x7) * 8);
    if (st) STAGE_PAIR(r2, kk2, 2);
    __builtin_amdgcn_s_barrier();
    asm volatile("s_waitcnt lgkmcnt(0)" ::: "memory");
    __builtin_amdgcn_s_setprio(1);
    #pragma unroll
    for (int i = 0; i < 2; ++i)
      #pragma unroll
      for (int j = 0; j < 2; ++j)
        #pragma unroll
        for (int t2 = 0; t2 < 2; ++t2)
          acc[i + 2][j] = __builtin_amdgcn_mfma_f32_16x16x32_bf16(a1[i][t2], b0[j][t2], acc[i + 2][j], 0, 0, 0);
    __builtin_amdgcn_s_setprio(0);
    __builtin_amdgcn_s_barrier();

    // ---- P3: quadrant (i=2..3, j=2..3). Load B23; reuse A23; 2 DMA.
    #pragma unroll
    for (int j = 0; j < 2; ++j)
      #pragma unroll
      for (int t2 = 0; t2 < 2; ++t2)
        b1[j][t2] = *(const short8*)(sB + (wn + (j + 2) * 16 + lr) * 64 + (((t2 << 2) | q) ^ x7) * 8);
    if (st) STAGE_PAIR(r2, kk2, 4);
    __builtin_amdgcn_s_barrier();
    asm volatile("s_waitcnt lgkmcnt(0)" ::: "memory");
    __builtin_amdgcn_s_setprio(1);
    #pragma unroll
    for (int i = 0; i < 2; ++i)
      #pragma unroll
      for (int j = 0; j < 2; ++j)
        #pragma unroll
        for (int t2 = 0; t2 < 2; ++t2)
          acc[i + 2][j + 2] = __builtin_amdgcn_mfma_f32_16x16x32_bf16(a1[i][t2], b1[j][t2], acc[i + 2][j + 2], 0, 0, 0);
    __builtin_amdgcn_s_setprio(0);
    __builtin_amdgcn_s_barrier();

    // ---- P4: quadrant (i=0..1, j=2..3). Reload A01; reuse B23.
    #pragma unroll
    for (int i = 0; i < 2; ++i)
      #pragma unroll
      for (int t2 = 0; t2 < 2; ++t2)
        a0[i][t2] = *(const short8*)(sA + (wm + i * 16 + lr) * 64 + (((t2 << 2) | q) ^ x7) * 8);
    __builtin_amdgcn_s_barrier();
    asm volatile("s_waitcnt lgkmcnt(0)" ::: "memory");
    __builtin_amdgcn_s_setprio(1);
    #pragma unroll
    for (int i = 0; i < 2; ++i)
      #pragma unroll
      for (int j = 0; j < 2; ++j)
        #pragma unroll
        for (int t2 = 0; t2 < 2; ++t2)
          acc[i][j + 2] = __builtin_amdgcn_mfma_f32_16x16x32_bf16(a0[i][t2], b1[j][t2], acc[i][j + 2], 0, 0, 0);
    __builtin_amdgcn_s_setprio(0);

    // ---- tile boundary: identical ledger to R12/R14 (verified twice).
    if (st) { asm volatile("s_waitcnt vmcnt(6)" ::: "memory"); }
    else    { asm volatile("s_waitcnt vmcnt(0)" ::: "memory"); }
    __builtin_amdgcn_s_barrier();
    r0 = (r0 + 1 >= 3) ? 0 : r0 + 1;
  }

  #pragma unroll
  for (int i = 0; i < 4; ++i)
    #pragma unroll
    for (int j = 0; j < 4; ++j) {
      size_t col = n0 + wn + j * 16 + lr;
      float bv = bias[col];
      #pragma unroll
      for (int r = 0; r < 4; ++r) {
        size_t row = m0 + wm + i * 16 + q * 4 + r;
        float v = acc[i][j][r] + bv;
        v = v > 0.f ? v : 0.f;
        if (sizeof(OUT) == 2) ((unsigned short*)C)[row * N + col] = f2bf(v);
        else                  ((float*)C)[row * N + col] = v;
      }
    }
}

// ---------------------------------------------------------------------------
// GEMM (legacy 128-tile, used for GEMM3 only): C = relu(A @ Bw^T + bias).
// ---------------------------------------------------------------------------
template<int BM, int BN, int WM, int WN, typename OUT>
__global__ __launch_bounds__(256) void gemm_async(
    const unsigned short* __restrict__ A, const unsigned short* __restrict__ Bw,
    const float* __restrict__ bias, OUT* __restrict__ C,
    int M, int N, int K)
{
  constexpr int BK = 64;
  __shared__ __align__(16) unsigned short lA[BM * BK];
  __shared__ __align__(16) unsigned short lB[BN * BK];
  const int tid = threadIdx.x;
  const int lane = tid & 63;
  const int wv = tid >> 6;
  const int q = lane >> 4, lr = lane & 15;
  const int x7 = lr & 7;
  constexpr int WN_CNT = BN / WN;
  const int wm = (wv / WN_CNT) * WM;
  const int wn = (wv % WN_CNT) * WN;
  const size_t m0 = (size_t)blockIdx.x * BM;
  const size_t n0 = (size_t)blockIdx.y * BN;
  constexpr int MI = WM / 16, NI = WN / 16;
  f32x4 acc[MI][NI] = {};
  constexpr int A_INSTR = BM * BK / 512;   // 1024B DMA instructions
  constexpr int B_INSTR = BN * BK / 512;
  constexpr int A_PW = A_INSTR / 4, B_PW = B_INSTR / 4;
  (void)M;

  for (int k0 = 0; k0 < K; k0 += BK) {
    __syncthreads();
    #pragma unroll
    for (int s = 0; s < A_PW; ++s) {
      int instr = wv * A_PW + s;
      int pc = instr * 64 + lane;
      int row = pc >> 3, col = pc & 7;
      int lc = col ^ (row & 7);
      gl2lds16(A + (m0 + row) * K + k0 + lc * 8, lA + instr * 512);
    }
    #pragma unroll
    for (int s = 0; s < B_PW; ++s) {
      int instr = wv * B_PW + s;
      int pc = instr * 64 + lane;
      int row = pc >> 3, col = pc & 7;
      int lc = col ^ (row & 7);
      gl2lds16(Bw + (n0 + row) * K + k0 + lc * 8, lB + instr * 512);
    }
    __syncthreads();
    #pragma unroll
    for (int t = 0; t < 2; ++t) {
      short8 af[MI], bfr[NI];
      #pragma unroll
      for (int i = 0; i < MI; ++i) {
        int r = wm + i * 16 + lr;
        af[i] = *(const short8*)(lA + r * 64 + (((t << 2) | q) ^ x7) * 8);
      }
      #pragma unroll
      for (int j = 0; j < NI; ++j) {
        int r = wn + j * 16 + lr;
        bfr[j] = *(const short8*)(lB + r * 64 + (((t << 2) | q) ^ x7) * 8);
      }
      #pragma unroll
      for (int i = 0; i < MI; ++i)
        #pragma unroll
        for (int j = 0; j < NI; ++j)
          acc[i][j] = __builtin_amdgcn_mfma_f32_16x16x32_bf16(af[i], bfr[j], acc[i][j], 0, 0, 0);
    }
  }
  #pragma unroll
  for (int i = 0; i < MI; ++i)
    #pragma unroll
    for (int j = 0; j < NI; ++j) {
      size_t col = n0 + wn + j * 16 + lr;
      float bv = bias[col];
      #pragma unroll
      for (int r = 0; r < 4; ++r) {
        size_t row = m0 + wm + i * 16 + q * 4 + r;
        float v = acc[i][j][r] + bv;
        v = v > 0.f ? v : 0.f;
        if (sizeof(OUT) == 2) ((unsigned short*)C)[row * N + col] = f2bf(v);
        else                  ((float*)C)[row * N + col] = v;
      }
    }
}

// ---------------------------------------------------------------------------
// Precompute (parallel): block 0 -> Ap/Am/b2c; blocks 1..16 -> Qt (TRANSPOSED)
// ---------------------------------------------------------------------------
__global__ __launch_bounds__(256) void precompute(
    const float* __restrict__ w0, const float* __restrict__ w1,
    const float* __restrict__ l2W, const float* __restrict__ l2b,
    float2* __restrict__ Ap, float2* __restrict__ Am,
    float2* __restrict__ Qt, float2* __restrict__ b2c)
{
  const int t = threadIdx.x;
  const int blk = blockIdx.x;
  if (blk == 0) {
    if (t < 64) {
      float apx = 0, apy = 0, amx = 0, amy = 0;
      for (int m = 0; m < 32; ++m) {
        float s0 = w0[m * 64 + t];
        float cf = w1[m * 64 + t] * s0;
        float sn, cs; sincosf(PI2F * (float)m / 32.f, &sn, &cs);
        if (s0 > 0.f)      { apx += cs * cf; apy += sn * cf; }
        else if (s0 < 0.f) { amx += cs * cf; amy += sn * cf; }
      }
      Ap[t] = make_float2(apx, apy);
      Am[t] = make_float2(amx, amy);
      float bx = 0, by = 0;
      for (int k = 0; k < 64; ++k) {
        float sn, cs; sincosf(PI2F * (float)((t * k) & 63) / 64.f, &sn, &cs);
        float lb = l2b[k] * (1.f / 64.f);
        bx += cs * lb; by += sn * lb;
      }
      b2c[t] = make_float2(bx, by);
    }
  } else {
    int e = (blk - 1) * 256 + t;
    int j = e >> 6, w = e & 63;
    float qx = 0, qy = 0;
    for (int k = 0; k < 64; ++k) {
      float sn, cs; sincosf(PI2F * (float)((j * k) & 63) / 64.f, &sn, &cs);
      float lw = l2W[k * 64 + w] * (1.f / 64.f);
      qx += cs * lw; qy += sn * lw;
    }
    Qt[w * 64 + j] = make_float2(qx, qy);   // transposed store
  }
}

// ---------------------------------------------------------------------------
// DFT along axis1 (64-pt forward). 1024 blocks x 32 rows; unroll-by-4.
// ---------------------------------------------------------------------------
__global__ __launch_bounds__(256) void dft64_rows(
    const float* __restrict__ x3, float2* __restrict__ xh1)
{
  __shared__ __align__(16) float xt[32][64];
  __shared__ float2 tw[64];
  const int t = threadIdx.x;
  const size_t b0 = (size_t)blockIdx.x * 32;
  for (int it = 0; it < 8; ++it) {
    int idx = it * 256 + t;
    int r = idx >> 6, w = idx & 63;
    xt[r][w] = x3[(b0 + r) * 64 + w];
  }
  if (t < 64) {
    float sn, cs; sincosf(-PI2F * (float)t / 64.f, &sn, &cs);
    tw[t] = make_float2(cs, sn);
  }
  __syncthreads();
  const int k = t & 63, rg = t >> 6;
  float2 acc[8] = {};
  #pragma unroll 1
  for (int w4 = 0; w4 < 16; ++w4) {
    int w = 4 * w4;
    int kw = k * w;
    float2 t0 = tw[kw & 63];
    float2 t1 = tw[(kw + k) & 63];
    float2 t2 = tw[(kw + 2 * k) & 63];
    float2 t3 = tw[(kw + 3 * k) & 63];
    #pragma unroll
    for (int r = 0; r < 8; ++r) {
      float4 xv = *(const float4*)(&xt[rg * 8 + r][w]);
      acc[r].x += xv.x * t0.x + xv.y * t1.x + xv.z * t2.x + xv.w * t3.x;
      acc[r].y += xv.x * t0.y + xv.y * t1.y + xv.z * t2.y + xv.w * t3.y;
    }
  }
  #pragma unroll
  for (int r = 0; r < 8; ++r)
    xh1[(b0 + rg * 8 + r) * 64 + k] = acc[r];
}

// ---------------------------------------------------------------------------
// Batch-axis FFT stage 1: 128-pt DFT over b1 as radix-16 x radix-8, then
// inter-stage twiddle W32768^{b2*k1}. One thread = one full 16-pt DFT from
// 16 register-resident inputs; register twiddles; incremental rotations.
// ---------------------------------------------------------------------------
template<int SIGN>
__global__ __launch_bounds__(256) void fft_stage1(
    const float2* __restrict__ Xin, float2* __restrict__ T)
{
  __shared__ __align__(16) float2 tile[128 * 34];
  __shared__ float2 tw16s[16];
  const int blk = blockIdx.x;
  const int b2 = blk >> 1, wh = (blk & 1) * 32;
  const int t = threadIdx.x;
  #pragma unroll
  for (int it = 0; it < 8; ++it) {
    int idx = it * 256 + t;
    int b1 = idx >> 4, wi = (idx & 15) * 2;
    float4 v = *(const float4*)&Xin[((size_t)(b1 * 256 + b2)) * 64 + wh + wi];
    *(float4*)&tile[b1 * 34 + wi] = v;
  }
  if (t < 16) {
    float sn, cs; sincosf(SIGN * PI2F * (float)t / 16.f, &sn, &cs);
    tw16s[t] = make_float2(cs, sn);
  }
  __syncthreads();
  float2 twr[16];
  #pragma unroll
  for (int j = 0; j < 16; ++j) twr[j] = tw16s[j];

  // ---- phase A: thread (n2a = t>>5, w = t&31): full radix-16 DFT over n1
  {
    const int n2a = t >> 5, w = t & 31;
    float2 d[16];
    #pragma unroll
    for (int n1 = 0; n1 < 16; ++n1)
      d[n1] = tile[(8 * n1 + n2a) * 34 + w];
    float2 y[16];
    #pragma unroll
    for (int k = 0; k < 16; ++k) {
      float2 a = d[0];                         // n1=0: tw=(1,0) exact
      #pragma unroll
      for (int n1 = 1; n1 < 16; ++n1) {
        float2 tv = twr[(n1 * k) & 15];        // constant index after unroll
        a.x += d[n1].x * tv.x - d[n1].y * tv.y;
        a.y += d[n1].x * tv.y + d[n1].y * tv.x;
      }
      y[k] = a;
    }
    float sstep, cstep;                        // W128^{n2a*k}, incremental
    sincosf(SIGN * PI2F * (float)n2a / 128.f, &sstep, &cstep);
    float2 rot = make_float2(1.f, 0.f);
    #pragma unroll
    for (int k = 0; k < 16; ++k) {
      float2 a = y[k];
      y[k] = make_float2(a.x * rot.x - a.y * rot.y, a.x * rot.y + a.y * rot.x);
      float nrx = rot.x * cstep - rot.y * sstep;
      rot.y = rot.x * sstep + rot.y * cstep;
      rot.x = nrx;
    }
    __syncthreads();                           // all reads of tile done
    #pragma unroll
    for (int k = 0; k < 16; ++k)
      tile[(n2a * 16 + k) * 34 + w] = y[k];
  }
  __syncthreads();                             // y visible

  // ---- phase B: thread (wB = t&31, qB = t>>5); radix-8 over n2
  const int wB = t & 31, qB = t >> 5;
  float sstep, cstep;
  sincosf(SIGN * PI2F * (float)(16 * b2) / 32768.f, &sstep, &cstep);
  #pragma unroll
  for (int h = 0; h < 2; ++h) {
    const int k1p = qB + 8 * h;
    float2 d[8];
    #pragma unroll
    for (int n2 = 0; n2 < 8; ++n2)
      d[n2] = tile[(n2 * 16 + k1p) * 34 + wB];
    float2 acc[8];
    #pragma unroll
    for (int k2p = 0; k2p < 8; ++k2p) {
      float2 a = d[0];
      #pragma unroll
      for (int n2 = 1; n2 < 8; ++n2) {
        float2 tv = twr[(2 * n2 * k2p) & 15];  // W8^{n2 k2p}, reg twiddle
        a.x += d[n2].x * tv.x - d[n2].y * tv.y;
        a.y += d[n2].x * tv.y + d[n2].y * tv.x;
      }
      acc[k2p] = a;
    }
    float sb, cb;
    sincosf(SIGN * PI2F * (float)(b2 * k1p) / 32768.f, &sb, &cb);
    float2 rot = make_float2(cb, sb);
    #pragma unroll
    for (int k2p = 0; k2p < 8; ++k2p) {
      int k1 = k1p + 16 * k2p;
      float2 a = acc[k2p];
      T[((size_t)k1 * 256 + b2) * 64 + wh + wB] =
          make_float2(a.x * rot.x - a.y * rot.y, a.x * rot.y + a.y * rot.x);
      float nrx = rot.x * cstep - rot.y * sstep;
      rot.y = rot.x * sstep + rot.y * cstep;
      rot.x = nrx;
    }
  }
}

// ---------------------------------------------------------------------------
// Batch-axis FFT stage 2: 256-pt DFT over b2 as radix-16 x radix-16.
// ---------------------------------------------------------------------------
template<int SIGN, bool SCALE>
__global__ __launch_bounds__(256) void fft_stage2(
    const float2* __restrict__ T, float2* __restrict__ X)
{
  __shared__ __align__(16) float2 tile[256 * 18];
  __shared__ float2 tw16s[16];
  const int blk = blockIdx.x;
  const int k1 = blk >> 2, wq = (blk & 3) * 16;
  const int t = threadIdx.x;
  #pragma unroll
  for (int it = 0; it < 8; ++it) {
    int idx = it * 256 + t;
    int r2 = idx >> 3, wi = (idx & 7) * 2;
    float4 v = *(const float4*)&T[((size_t)k1 * 256 + r2) * 64 + wq + wi];
    *(float4*)&tile[r2 * 18 + wi] = v;
  }
  if (t < 16) {
    float sn, cs; sincosf(SIGN * PI2F * (float)t / 16.f, &sn, &cs);
    tw16s[t] = make_float2(cs, sn);
  }
  __syncthreads();
  float2 twr[16];
  #pragma unroll
  for (int j = 0; j < 16; ++j) twr[j] = tw16s[j];

  // ---- phase A: thread (n2a = t>>4, w = t&15): radix-16 DFT over n1
  {
    const int n2a = t >> 4, w = t & 15;
    float2 d[16];
    #pragma unroll
    for (int n1 = 0; n1 < 16; ++n1)
      d[n1] = tile[(16 * n1 + n2a) * 18 + w];
    float2 y[16];
    #pragma unroll
    for (int k = 0; k < 16; ++k) {
      float2 a = d[0];
      #pragma unroll
      for (int n1 = 1; n1 < 16; ++n1) {
        float2 tv = twr[(n1 * k) & 15];
        a.x += d[n1].x * tv.x - d[n1].y * tv.y;
        a.y += d[n1].x * tv.y + d[n1].y * tv.x;
      }
      y[k] = a;
    }
    float sstep, cstep;                        // W256^{n2a*k}, incremental
    sincosf(SIGN * PI2F * (float)n2a / 256.f, &sstep, &cstep);
    float2 rot = make_float2(1.f, 0.f);
    #pragma unroll
    for (int k = 0; k < 16; ++k) {
      float2 a = y[k];
      y[k] = make_float2(a.x * rot.x - a.y * rot.y, a.x * rot.y + a.y * rot.x);
      float nrx = rot.x * cstep - rot.y * sstep;
      rot.y = rot.x * sstep + rot.y * cstep;
      rot.x = nrx;
    }
    __syncthreads();                           // all reads done
    #pragma unroll
    for (int k = 0; k < 16; ++k)
      tile[(n2a * 16 + k) * 18 + w] = y[k];
  }
  __syncthreads();                             // y visible

  // ---- phase B: thread (k1pb = t>>4, wB = t&15): radix-16 DFT over n2
  const int k1pb = t >> 4, wB = t & 15;
  float2 d[16];
  #pragma unroll
  for (int n2 = 0; n2 < 16; ++n2)
    d[n2] = tile[(n2 * 16 + k1pb) * 18 + wB];
  const float sc = SCALE ? (1.f / 32768.f) : 1.f;
  #pragma unroll
  for (int k2p = 0; k2p < 16; ++k2p) {
    float2 a = d[0];
    #pragma unroll
    for (int n2 = 1; n2 < 16; ++n2) {
      float2 tv = twr[(n2 * k2p) & 15];
      a.x += d[n2].x * tv.x - d[n2].y * tv.y;
      a.y += d[n2].x * tv.y + d[n2].y * tv.x;
    }
    int k2 = k1pb + 16 * k2p;
    size_t row = (size_t)(k1 + 128 * k2);
    X[row * 64 + wq + wB] = make_float2(a.x * sc, a.y * sc);
  }
}

// ---------------------------------------------------------------------------
// Pointwise A+/- fold, lin1 crelu, Q-fold (ifft64+lin2).
// ---------------------------------------------------------------------------
__global__ __launch_bounds__(256) void pw_lin(
    const float2* __restrict__ xh,
    const float2* __restrict__ Ap, const float2* __restrict__ Am,
    const float* __restrict__ l1W, const float* __restrict__ l1b,
    const float2* __restrict__ Qt, const float2* __restrict__ b2c,
    float2* __restrict__ u)
{
  __shared__ __align__(16) float2 tile[32][64];   // y, then z in place
  __shared__ __align__(16) float2 qt[64 * 64];    // Qt[w][j], 32KB
  const int t = threadIdx.x;
  const int lane = t & 63;
  const int wv = t >> 6;
  const size_t b0 = (size_t)blockIdx.x * 32;

  // stage Qt (32KB) via async DMA: 32 x 1KB instrs, 8 per wave
  #pragma unroll
  for (int s = 0; s < 8; ++s) {
    int instr = wv * 8 + s;
    gl2lds16((const char*)Qt + instr * 1024 + lane * 16,
             (const char*)qt + instr * 1024);
  }

  // phase 0: pointwise A+/- fold -> y
  for (int it = 0; it < 8; ++it) {
    int idx = it * 256 + t;
    int r = idx >> 6, w = idx & 63;
    float2 xv = xh[(b0 + r) * 64 + w];
    float2 Aa = (xv.x >= 0.f) ? Ap[w] : Am[w];
    float2 Ab = (xv.y >= 0.f) ? Ap[w] : Am[w];
    tile[r][w] = make_float2(xv.x * Aa.x - xv.y * Ab.y,
                             xv.x * Aa.y + xv.y * Ab.x);
  }
  __syncthreads();   // y visible to all waves; Qt DMA drained (vmcnt0)

  const int n = lane, rg = wv;   // wave rg owns tile rows [8rg, 8rg+8)

  // lin1: z[r][n] = crelu(sum_w y[r][w] * l1W[n][w] + b[n]); in place.
  {
    float2 acc[8] = {};
    const float* wrow = l1W + n * 64;
    float4 lwn = *(const float4*)wrow;             // rolling prefetch
    #pragma unroll 1
    for (int w2 = 0; w2 < 16; ++w2) {
      float4 lw = lwn;
      lwn = *(const float4*)(wrow + 4 * ((w2 + 1) & 15));
      int w = 4 * w2;
      #pragma unroll
      for (int r = 0; r < 8; ++r) {
        const float4* rowp = (const float4*)(&tile[rg * 8 + r][w]);
        float4 y01 = rowp[0];                      // broadcast b128
        float4 y23 = rowp[1];
        acc[r].x += y01.x * lw.x + y01.z * lw.y + y23.x * lw.z + y23.z * lw.w;
        acc[r].y += y01.y * lw.x + y01.w * lw.y + y23.y * lw.z + y23.w * lw.w;
      }
    }
    float bb = l1b[n];
    #pragma unroll
    for (int r = 0; r < 8; ++r) {
      float zr = acc[r].x + bb; zr = zr > 0.f ? zr : 0.f;
      float zi = acc[r].y;      zi = zi > 0.f ? zi : 0.f;
      tile[rg * 8 + r][n] = make_float2(zr, zi);   // same-wave rows only
    }
  }

  // Q-fold: u[r][j] = sum_w z[r][w] * Qt[w][j] + b2c[j]
  {
    const int j = lane;
    float2 acc[8] = {};
    #pragma unroll 1
    for (int w2 = 0; w2 < 16; ++w2) {
      int w = 4 * w2;
      float2 q0 = qt[(w + 0) * 64 + j];            // contiguous per-lane b64
      float2 q1 = qt[(w + 1) * 64 + j];
      float2 q2 = qt[(w + 2) * 64 + j];
      float2 q3 = qt[(w + 3) * 64 + j];
      #pragma unroll
      for (int r = 0; r < 8; ++r) {
        const float4* rowp = (const float4*)(&tile[rg * 8 + r][w]);
        float4 z01 = rowp[0];                      // broadcast b128
        float4 z23 = rowp[1];
        acc[r].x += z01.x * q0.x - z01.y * q0.y
                  + z01.z * q1.x - z01.w * q1.y
                  + z23.x * q2.x - z23.y * q2.y
                  + z23.z * q3.x - z23.w * q3.y;
        acc[r].y += z01.x * q0.y + z01.y * q0.x
                  + z01.z * q1.y + z01.w * q1.x
                  + z23.x * q2.y + z23.y * q2.x
                  + z23.z * q3.y + z23.w * q3.x;
      }
    }
    float2 bc = b2c[j];
    #pragma unroll
    for (int r = 0; r < 8; ++r)
      u[(b0 + rg * 8 + r) * 64 + j] = make_float2(acc[r].x + bc.x, acc[r].y + bc.y);
  }
}

// ---------------------------------------------------------------------------
// Final W_out GEMM; MODE 0 = real only, MODE 1 = interleaved (re,im).
// ---------------------------------------------------------------------------
template<int MODE>
__global__ __launch_bounds__(256) void final_out(
    const float2* __restrict__ v, const float* __restrict__ Wout,
    const float* __restrict__ bout, float* __restrict__ out)
{
  __shared__ __align__(16) float2 vt[32][64];
  const int t = threadIdx.x;
  const size_t b0 = (size_t)blockIdx.x * 32;
  for (int it = 0; it < 8; ++it) {
    int idx = it * 256 + t;
    int r = idx >> 6, w = idx & 63;
    vt[r][w] = v[(b0 + r) * 64 + w];
  }
  __syncthreads();
  const int f = t & 127, rg = t >> 7;
  const float* wrow = Wout + f * 64;
  float2 acc[16] = {};
  float2 wvn = *(const float2*)wrow;               // rolling prefetch
  #pragma unroll 1
  for (int j2 = 0; j2 < 32; ++j2) {
    float2 wc = wvn;
    wvn = *(const float2*)(wrow + 2 * ((j2 + 1) & 31));
    #pragma unroll
    for (int r = 0; r < 16; ++r) {
      float4 vv = *(const float4*)(&vt[rg * 16 + r][2 * j2]);  // broadcast b128
      acc[r].x += vv.x * wc.x + vv.z * wc.y;
      acc[r].y += vv.y * wc.x + vv.w * wc.y;
    }
  }
  float bb = bout[f];
  #pragma unroll
  for (int r = 0; r < 16; ++r) {
    size_t idx = (b0 + rg * 16 + r) * 128 + f;
    if (MODE == 0) out[idx] = acc[r].x + bb;
    else ((float2*)out)[idx] = make_float2(acc[r].x + bb, acc[r].y);
  }
}

// ---------------------------------------------------------------------------
extern "C" void kernel_launch(void* const* d_in, const int* in_sizes, int n_in,
                              void* d_out, int out_size, void* d_ws, size_t ws_size,
                              hipStream_t stream)
{
  (void)in_sizes; (void)n_in; (void)ws_size;
  const float* geom = (const float*)d_in[0];
  const float* Win  = (const float*)d_in[1];
  const float* bin  = (const float*)d_in[2];
  const float* Wh1  = (const float*)d_in[3];
  const float* bh1  = (const float*)d_in[4];
  const float* Wh2  = (const float*)d_in[5];
  const float* bh2  = (const float*)d_in[6];
  const float* w0   = (const float*)d_in[7];
  const float* w1   = (const float*)d_in[8];
  const float* l1W  = (const float*)d_in[9];
  const float* l1b  = (const float*)d_in[10];
  const float* l2W  = (const float*)d_in[11];
  const float* l2b  = (const float*)d_in[12];
  const float* Wout = (const float*)d_in[13];
  const float* bout = (const float*)d_in[14];

  char* ws = (char*)d_ws;
  const size_t MB = 1048576ull;
  unsigned short* geomb = (unsigned short*)(ws);
  unsigned short* x2b   = (unsigned short*)(ws);
  unsigned short* x1b   = (unsigned short*)(ws + 32 * MB);
  float*  x3  = (float*)(ws + 32 * MB);
  float2* S0  = (float2*)(ws + 40 * MB);
  float2* S1  = (float2*)(ws + 56 * MB);
  float2* Ap  = (float2*)(ws + 72 * MB);
  float2* Am  = (float2*)(ws + 72 * MB + 512);
  float2* b2c = (float2*)(ws + 72 * MB + 1024);
  float2* Qt  = (float2*)(ws + 72 * MB + 1536);
  unsigned short* Winb = (unsigned short*)(ws + 96 * MB);
  unsigned short* Wh1b = (unsigned short*)(ws + 97 * MB);
  unsigned short* Wh2b = (unsigned short*)(ws + 98 * MB);

  f32_to_bf16_k<<<16384, 256, 0, stream>>>(geom, geomb, 4194304);
  f32_to_bf16_k<<<512, 256, 0, stream>>>(Win, Winb, 131072);
  f32_to_bf16_k<<<512, 256, 0, stream>>>(Wh1, Wh1b, 131072);
  f32_to_bf16_k<<<32, 256, 0, stream>>>(Wh2, Wh2b, 8192);

  // GEMM1: [32768,512] x [1024,512]^T -> bf16 [32768,1024]; 256 x 4 blocks
  gemm_pipe<2, unsigned short><<<1024, 512, 0, stream>>>(
      geomb, Winb, bin, x1b, 1024, 512);
  // GEMM2: [32768,1024] x [512,1024]^T -> bf16 [32768,512]; 256 x 2 blocks
  gemm_pipe<1, unsigned short><<<512, 512, 0, stream>>>(
      x1b, Wh1b, bh1, x2b, 512, 1024);
  // GEMM3: [32768,512] x [64,512]^T -> f32 [32768,64]
  gemm_async<128, 64,64,32,float><<<dim3(256, 1), 256, 0, stream>>>(
      x2b, Wh2b, bh2, x3, 32768, 64, 512);

  precompute<<<17, 256, 0, stream>>>(w0, w1, l2W, l2b, Ap, Am, Qt, b2c);
  dft64_rows<<<1024, 256, 0, stream>>>(x3, S0);
  fft_stage1<-1><<<512, 256, 0, stream>>>(S0, S1);
  fft_stage2<-1, false><<<512, 256, 0, stream>>>(S1, S0);
  pw_lin<<<1024, 256, 0, stream>>>(S0, Ap, Am, l1W, l1b, Qt, b2c, S1);
  fft_stage1<1><<<512, 256, 0, stream>>>(S1, S0);
  fft_stage2<1, true><<<512, 256, 0, stream>>>(S0, S1);
  if (out_size >= 8388608) {
    final_out<1><<<1024, 256, 0, stream>>>(S1, Wout, bout, (float*)d_out);
  } else {
    final_out<0><<<1024, 256, 0, stream>>>(S1, Wout, bout, (float*)d_out);
  }
}

// Round 11
// 413.139 us; speedup vs baseline: 1.0282x; 1.0282x over previous
//
#include <hip/hip_runtime.h>
#include <hip/hip_bf16.h>

// ---------------------------------------------------------------------------
// FieldPredictionNetwork. R16: R15 fine-phase GEMM REGRESSED (58us vs R14's
// 52.2, MfmaUtil 22%) — third schedule variant at the ~650TF non-m201
// ceiling; per pre-commitment GEMM structure is now FROZEN at the R14
// merged-region variant (best measured). This round, low-risk wins:
//  1. gemm_pipe reverted to R14 (52.2us measured).
//  2. conv_all fusion restored (R14-proven; -3 launches).
//  3. dft64_rows FUSED into GEMM3 (gemm3_dft): block already holds the full
//     128x64 rows; epilogue -> padded LDS [128][68] -> barrier -> R13 DFT
//     (identical arithmetic order) -> S0. Kills one launch + 16MB x3
//     round-trip + the latency-bound dft64 pass.
// ---------------------------------------------------------------------------

#define PI2F 6.28318530717958647692f

typedef __attribute__((ext_vector_type(8))) short short8;
typedef __attribute__((ext_vector_type(4))) float f32x4;

__device__ __forceinline__ unsigned short f2bf(float f) {
  unsigned int u = __float_as_uint(f);
  u += 0x7fff + ((u >> 16) & 1);          // RN-even
  return (unsigned short)(u >> 16);
}
__device__ __forceinline__ unsigned int pack_bf16x2(float a, float b) {
  return (unsigned int)f2bf(a) | ((unsigned int)f2bf(b) << 16);
}

// async 16B global->LDS DMA; lds dest must be wave-uniform (HW adds lane*16)
__device__ __forceinline__ void gl2lds16(const void* gptr, const void* lptr) {
  __builtin_amdgcn_global_load_lds(
      (const __attribute__((address_space(1))) unsigned int*)(unsigned long long)gptr,
      (__attribute__((address_space(3))) unsigned int*)(unsigned int)(unsigned long long)lptr,
      16, 0, 0);
}

// ---------------------------------------------------------------------------
// Fused f32 -> bf16 pack: geom (16384 blocks) + Win + Wh1 + Wh2 in one launch
// ---------------------------------------------------------------------------
__global__ __launch_bounds__(256) void conv_all(
    const float* __restrict__ geom, const float* __restrict__ Win,
    const float* __restrict__ Wh1, const float* __restrict__ Wh2,
    unsigned short* __restrict__ dg, unsigned short* __restrict__ dw,
    unsigned short* __restrict__ d1, unsigned short* __restrict__ d2)
{
  int i = blockIdx.x * 256 + threadIdx.x;
  const float* s; unsigned short* d; int off;
  if (i < 4194304)      { s = geom; d = dg; off = i; }
  else if (i < 4325376) { s = Win;  d = dw; off = i - 4194304; }
  else if (i < 4456448) { s = Wh1;  d = d1; off = i - 4325376; }
  else if (i < 4464640) { s = Wh2;  d = d2; off = i - 4456448; }
  else return;
  float4 v = ((const float4*)s)[off];
  uint2 p;
  p.x = pack_bf16x2(v.x, v.y);
  p.y = pack_bf16x2(v.z, v.w);
  ((uint2*)d)[off] = p;
}

// ---------------------------------------------------------------------------
// R14 pipelined GEMM (frozen): C = relu(A @ Bw^T + bias). A [M,K], Bw [N,K]
// bf16. BM=128, BN=256, BK=64. 3-buffer LDS ring (144KB), counted vmcnt,
// 8 waves, ONE barrier per k-tile; reads+stage+MFMA merged.
// 1D grid, nwg = (M/128)*(N/256), nwg % 8 == 0 required (XCD swizzle).
// ---------------------------------------------------------------------------
template<int NBLOG, typename OUT>
__global__ __launch_bounds__(512, 1) void gemm_pipe(
    const unsigned short* __restrict__ A, const unsigned short* __restrict__ Bw,
    const float* __restrict__ bias, OUT* __restrict__ C, int N, int K)
{
  constexpr int BM = 128, BN = 256, BK = 64;
  constexpr int ASZ = BM * BK;            // 8192 elems = 16 KB
  constexpr int BSZ = BN * BK;            // 16384 elems = 32 KB
  constexpr int BUF = ASZ + BSZ;          // 48 KB
  __shared__ __align__(16) unsigned short lds[3 * BUF];   // 144 KB

  // T1: bijective XCD swizzle (nwg multiple of 8) -> contiguous chunk per XCD
  const int nwg = gridDim.x;
  const int cpx = nwg >> 3;
  const int orig = blockIdx.x;
  const int wg = (orig & 7) * cpx + (orig >> 3);
  const int mb = wg >> NBLOG;
  const int nb = wg & ((1 << NBLOG) - 1);
  const size_t m0 = (size_t)mb * BM;
  const size_t n0 = (size_t)nb * BN;

  const int tid = threadIdx.x;
  const int lane = tid & 63;
  const int wv = tid >> 6;
  const int q = lane >> 4, lr = lane & 15;
  const int x7 = lr & 7;
  const int wm = (wv >> 2) * 64;          // 2 M-positions
  const int wn = (wv & 3) * 64;           // 4 N-positions
  f32x4 acc[4][4] = {};

  // stage this wave's 6 DMA instrs for one k-tile into ring buffer r.
  auto STAGE = [&](int r, int kk) {
    unsigned short* dA = lds + r * BUF;
    #pragma unroll
    for (int u = 0; u < 6; ++u) {
      int e = wv * 6 + u;
      int isA = (e < 16) ? 1 : 0;
      int e2 = isA ? e : e - 16;
      int pc = e2 * 64 + lane;
      int row = pc >> 3, col = pc & 7;
      int lc = col ^ (row & 7);
      const unsigned short* src = isA ? A : Bw;
      size_t rb = isA ? m0 : n0;
      unsigned short* dst = dA + (isA ? 0 : ASZ) + e2 * 512;
      gl2lds16(src + (rb + row) * (size_t)K + kk + lc * 8, dst);
    }
  };

  const int nt = K / BK;                  // 8 or 16 here
  STAGE(0, 0);
  STAGE(1, BK);
  asm volatile("s_waitcnt vmcnt(6)" ::: "memory");
  __builtin_amdgcn_s_barrier();

  int r0 = 0;
  for (int t = 0; t < nt; ++t) {
    const unsigned short* sA = lds + r0 * BUF;
    const unsigned short* sB = sA + ASZ;
    const bool st = (t + 2) < nt;
    const int r2 = (r0 >= 1) ? (r0 - 1) : 2;    // (t+2)%3
    const int kk2 = (t + 2) * BK;

    short8 af[4][2], bfr[4][2];
    #pragma unroll
    for (int i = 0; i < 4; ++i)
      #pragma unroll
      for (int t2 = 0; t2 < 2; ++t2)
        af[i][t2] = *(const short8*)(sA + (wm + i * 16 + lr) * 64 + (((t2 << 2) | q) ^ x7) * 8);
    #pragma unroll
    for (int j = 0; j < 4; ++j)
      #pragma unroll
      for (int t2 = 0; t2 < 2; ++t2)
        bfr[j][t2] = *(const short8*)(sB + (wn + j * 16 + lr) * 64 + (((t2 << 2) | q) ^ x7) * 8);
    if (st) STAGE(r2, kk2);
    __builtin_amdgcn_s_setprio(1);
    #pragma unroll
    for (int i = 0; i < 4; ++i)
      #pragma unroll
      for (int j = 0; j < 4; ++j)
        #pragma unroll
        for (int t2 = 0; t2 < 2; ++t2)
          acc[i][j] = __builtin_amdgcn_mfma_f32_16x16x32_bf16(af[i][t2], bfr[j][t2], acc[i][j], 0, 0, 0);
    __builtin_amdgcn_s_setprio(0);

    asm volatile("s_waitcnt lgkmcnt(0)" ::: "memory");
    if (st) { asm volatile("s_waitcnt vmcnt(6)" ::: "memory"); }
    else    { asm volatile("s_waitcnt vmcnt(0)" ::: "memory"); }
    __builtin_amdgcn_s_barrier();
    r0 = (r0 + 1 >= 3) ? 0 : r0 + 1;
  }

  #pragma unroll
  for (int i = 0; i < 4; ++i)
    #pragma unroll
    for (int j = 0; j < 4; ++j) {
      size_t col = n0 + wn + j * 16 + lr;
      float bv = bias[col];
      #pragma unroll
      for (int r = 0; r < 4; ++r) {
        size_t row = m0 + wm + i * 16 + q * 4 + r;
        float v = acc[i][j][r] + bv;
        v = v > 0.f ? v : 0.f;
        if (sizeof(OUT) == 2) ((unsigned short*)C)[row * N + col] = f2bf(v);
        else                  ((float*)C)[row * N + col] = v;
      }
    }
}

// ---------------------------------------------------------------------------
// R16 fused GEMM3 + row-DFT: x3 = relu(x2 @ Wh2^T + bh2) [128 rows/block,
// all 64 cols in-block] -> LDS [128][68] -> 64-pt forward DFT along w
// (identical arithmetic to the verified dft64_rows) -> S0 complex.
// Grid 256 blocks x 256 threads. K=512. Saves the x3 global round-trip.
// ---------------------------------------------------------------------------
__global__ __launch_bounds__(256) void gemm3_dft(
    const unsigned short* __restrict__ A, const unsigned short* __restrict__ Bw,
    const float* __restrict__ bias, float2* __restrict__ S0, int K)
{
  constexpr int BM = 128, BN = 64, BK = 64;
  __shared__ __align__(16) unsigned short lA[BM * BK];   // 16 KB
  __shared__ __align__(16) unsigned short lB[BN * BK];   // 8 KB
  __shared__ __align__(16) float xt[128][68];            // 34.8 KB (pad 68: 272B rows, 16B-aligned)
  __shared__ float2 tw[64];
  const int tid = threadIdx.x;
  const int lane = tid & 63;
  const int wv = tid >> 6;
  const int q = lane >> 4, lr = lane & 15;
  const int x7 = lr & 7;
  const int wm = (wv >> 1) * 64;          // 2 M-positions
  const int wn = (wv & 1) * 32;           // 2 N-positions
  const size_t m0 = (size_t)blockIdx.x * BM;
  f32x4 acc[4][2] = {};
  constexpr int A_PW = (BM * BK / 512) / 4;   // 4 instrs/wave
  constexpr int B_PW = (BN * BK / 512) / 4;   // 2 instrs/wave

  if (tid < 64) {
    float sn, cs; sincosf(-PI2F * (float)tid / 64.f, &sn, &cs);
    tw[tid] = make_float2(cs, sn);
  }

  for (int k0 = 0; k0 < K; k0 += BK) {
    __syncthreads();
    #pragma unroll
    for (int s = 0; s < A_PW; ++s) {
      int instr = wv * A_PW + s;
      int pc = instr * 64 + lane;
      int row = pc >> 3, col = pc & 7;
      int lc = col ^ (row & 7);
      gl2lds16(A + (m0 + row) * (size_t)K + k0 + lc * 8, lA + instr * 512);
    }
    #pragma unroll
    for (int s = 0; s < B_PW; ++s) {
      int instr = wv * B_PW + s;
      int pc = instr * 64 + lane;
      int row = pc >> 3, col = pc & 7;
      int lc = col ^ (row & 7);
      gl2lds16(Bw + (size_t)row * K + k0 + lc * 8, lB + instr * 512);
    }
    __syncthreads();
    #pragma unroll
    for (int t = 0; t < 2; ++t) {
      short8 af[4], bfr[2];
      #pragma unroll
      for (int i = 0; i < 4; ++i) {
        int r = wm + i * 16 + lr;
        af[i] = *(const short8*)(lA + r * 64 + (((t << 2) | q) ^ x7) * 8);
      }
      #pragma unroll
      for (int j = 0; j < 2; ++j) {
        int r = wn + j * 16 + lr;
        bfr[j] = *(const short8*)(lB + r * 64 + (((t << 2) | q) ^ x7) * 8);
      }
      #pragma unroll
      for (int i = 0; i < 4; ++i)
        #pragma unroll
        for (int j = 0; j < 2; ++j)
          acc[i][j] = __builtin_amdgcn_mfma_f32_16x16x32_bf16(af[i], bfr[j], acc[i][j], 0, 0, 0);
    }
  }

  // epilogue -> LDS (bias + relu), then in-block 64-pt DFT along w.
  __syncthreads();                         // all k-loop ds_reads retired
  #pragma unroll
  for (int i = 0; i < 4; ++i)
    #pragma unroll
    for (int j = 0; j < 2; ++j) {
      int col = wn + j * 16 + lr;
      float bv = bias[col];
      #pragma unroll
      for (int r = 0; r < 4; ++r) {
        int rowl = wm + i * 16 + q * 4 + r;
        float v = acc[i][j][r] + bv;
        xt[rowl][col] = v > 0.f ? v : 0.f;
      }
    }
  __syncthreads();                         // xt + tw visible

  const int k = tid & 63, rg = tid >> 6;   // rg owns rows [32rg, 32rg+32)
  #pragma unroll 1
  for (int half = 0; half < 2; ++half) {
    const int rb = rg * 32 + half * 16;
    float2 dacc[16] = {};
    #pragma unroll 1
    for (int w4 = 0; w4 < 16; ++w4) {
      int w = 4 * w4;
      int kw = k * w;
      float2 t0 = tw[kw & 63];
      float2 t1 = tw[(kw + k) & 63];
      float2 t2 = tw[(kw + 2 * k) & 63];
      float2 t3 = tw[(kw + 3 * k) & 63];
      #pragma unroll
      for (int r = 0; r < 16; ++r) {
        float4 xv = *(const float4*)(&xt[rb + r][w]);
        dacc[r].x += xv.x * t0.x + xv.y * t1.x + xv.z * t2.x + xv.w * t3.x;
        dacc[r].y += xv.x * t0.y + xv.y * t1.y + xv.z * t2.y + xv.w * t3.y;
      }
    }
    #pragma unroll
    for (int r = 0; r < 16; ++r)
      S0[(m0 + rb + r) * 64 + k] = dacc[r];
  }
}

// ---------------------------------------------------------------------------
// Precompute (parallel): block 0 -> Ap/Am/b2c; blocks 1..16 -> Qt (TRANSPOSED)
// ---------------------------------------------------------------------------
__global__ __launch_bounds__(256) void precompute(
    const float* __restrict__ w0, const float* __restrict__ w1,
    const float* __restrict__ l2W, const float* __restrict__ l2b,
    float2* __restrict__ Ap, float2* __restrict__ Am,
    float2* __restrict__ Qt, float2* __restrict__ b2c)
{
  const int t = threadIdx.x;
  const int blk = blockIdx.x;
  if (blk == 0) {
    if (t < 64) {
      float apx = 0, apy = 0, amx = 0, amy = 0;
      for (int m = 0; m < 32; ++m) {
        float s0 = w0[m * 64 + t];
        float cf = w1[m * 64 + t] * s0;
        float sn, cs; sincosf(PI2F * (float)m / 32.f, &sn, &cs);
        if (s0 > 0.f)      { apx += cs * cf; apy += sn * cf; }
        else if (s0 < 0.f) { amx += cs * cf; amy += sn * cf; }
      }
      Ap[t] = make_float2(apx, apy);
      Am[t] = make_float2(amx, amy);
      float bx = 0, by = 0;
      for (int k = 0; k < 64; ++k) {
        float sn, cs; sincosf(PI2F * (float)((t * k) & 63) / 64.f, &sn, &cs);
        float lb = l2b[k] * (1.f / 64.f);
        bx += cs * lb; by += sn * lb;
      }
      b2c[t] = make_float2(bx, by);
    }
  } else {
    int e = (blk - 1) * 256 + t;
    int j = e >> 6, w = e & 63;
    float qx = 0, qy = 0;
    for (int k = 0; k < 64; ++k) {
      float sn, cs; sincosf(PI2F * (float)((j * k) & 63) / 64.f, &sn, &cs);
      float lw = l2W[k * 64 + w] * (1.f / 64.f);
      qx += cs * lw; qy += sn * lw;
    }
    Qt[w * 64 + j] = make_float2(qx, qy);   // transposed store
  }
}

// ---------------------------------------------------------------------------
// Batch-axis FFT stage 1: 128-pt DFT over b1 as radix-16 x radix-8, then
// inter-stage twiddle W32768^{b2*k1}. One thread = one full 16-pt DFT from
// 16 register-resident inputs; register twiddles; incremental rotations.
// ---------------------------------------------------------------------------
template<int SIGN>
__global__ __launch_bounds__(256) void fft_stage1(
    const float2* __restrict__ Xin, float2* __restrict__ T)
{
  __shared__ __align__(16) float2 tile[128 * 34];
  __shared__ float2 tw16s[16];
  const int blk = blockIdx.x;
  const int b2 = blk >> 1, wh = (blk & 1) * 32;
  const int t = threadIdx.x;
  #pragma unroll
  for (int it = 0; it < 8; ++it) {
    int idx = it * 256 + t;
    int b1 = idx >> 4, wi = (idx & 15) * 2;
    float4 v = *(const float4*)&Xin[((size_t)(b1 * 256 + b2)) * 64 + wh + wi];
    *(float4*)&tile[b1 * 34 + wi] = v;
  }
  if (t < 16) {
    float sn, cs; sincosf(SIGN * PI2F * (float)t / 16.f, &sn, &cs);
    tw16s[t] = make_float2(cs, sn);
  }
  __syncthreads();
  float2 twr[16];
  #pragma unroll
  for (int j = 0; j < 16; ++j) twr[j] = tw16s[j];

  // ---- phase A: thread (n2a = t>>5, w = t&31): full radix-16 DFT over n1
  {
    const int n2a = t >> 5, w = t & 31;
    float2 d[16];
    #pragma unroll
    for (int n1 = 0; n1 < 16; ++n1)
      d[n1] = tile[(8 * n1 + n2a) * 34 + w];
    float2 y[16];
    #pragma unroll
    for (int k = 0; k < 16; ++k) {
      float2 a = d[0];                         // n1=0: tw=(1,0) exact
      #pragma unroll
      for (int n1 = 1; n1 < 16; ++n1) {
        float2 tv = twr[(n1 * k) & 15];        // constant index after unroll
        a.x += d[n1].x * tv.x - d[n1].y * tv.y;
        a.y += d[n1].x * tv.y + d[n1].y * tv.x;
      }
      y[k] = a;
    }
    float sstep, cstep;                        // W128^{n2a*k}, incremental
    sincosf(SIGN * PI2F * (float)n2a / 128.f, &sstep, &cstep);
    float2 rot = make_float2(1.f, 0.f);
    #pragma unroll
    for (int k = 0; k < 16; ++k) {
      float2 a = y[k];
      y[k] = make_float2(a.x * rot.x - a.y * rot.y, a.x * rot.y + a.y * rot.x);
      float nrx = rot.x * cstep - rot.y * sstep;
      rot.y = rot.x * sstep + rot.y * cstep;
      rot.x = nrx;
    }
    __syncthreads();                           // all reads of tile done
    #pragma unroll
    for (int k = 0; k < 16; ++k)
      tile[(n2a * 16 + k) * 34 + w] = y[k];
  }
  __syncthreads();                             // y visible

  // ---- phase B: thread (wB = t&31, qB = t>>5); radix-8 over n2
  const int wB = t & 31, qB = t >> 5;
  float sstep, cstep;
  sincosf(SIGN * PI2F * (float)(16 * b2) / 32768.f, &sstep, &cstep);
  #pragma unroll
  for (int h = 0; h < 2; ++h) {
    const int k1p = qB + 8 * h;
    float2 d[8];
    #pragma unroll
    for (int n2 = 0; n2 < 8; ++n2)
      d[n2] = tile[(n2 * 16 + k1p) * 34 + wB];
    float2 acc[8];
    #pragma unroll
    for (int k2p = 0; k2p < 8; ++k2p) {
      float2 a = d[0];
      #pragma unroll
      for (int n2 = 1; n2 < 8; ++n2) {
        float2 tv = twr[(2 * n2 * k2p) & 15];  // W8^{n2 k2p}, reg twiddle
        a.x += d[n2].x * tv.x - d[n2].y * tv.y;
        a.y += d[n2].x * tv.y + d[n2].y * tv.x;
      }
      acc[k2p] = a;
    }
    float sb, cb;
    sincosf(SIGN * PI2F * (float)(b2 * k1p) / 32768.f, &sb, &cb);
    float2 rot = make_float2(cb, sb);
    #pragma unroll
    for (int k2p = 0; k2p < 8; ++k2p) {
      int k1 = k1p + 16 * k2p;
      float2 a = acc[k2p];
      T[((size_t)k1 * 256 + b2) * 64 + wh + wB] =
          make_float2(a.x * rot.x - a.y * rot.y, a.x * rot.y + a.y * rot.x);
      float nrx = rot.x * cstep - rot.y * sstep;
      rot.y = rot.x * sstep + rot.y * cstep;
      rot.x = nrx;
    }
  }
}

// ---------------------------------------------------------------------------
// Batch-axis FFT stage 2: 256-pt DFT over b2 as radix-16 x radix-16.
// ---------------------------------------------------------------------------
template<int SIGN, bool SCALE>
__global__ __launch_bounds__(256) void fft_stage2(
    const float2* __restrict__ T, float2* __restrict__ X)
{
  __shared__ __align__(16) float2 tile[256 * 18];
  __shared__ float2 tw16s[16];
  const int blk = blockIdx.x;
  const int k1 = blk >> 2, wq = (blk & 3) * 16;
  const int t = threadIdx.x;
  #pragma unroll
  for (int it = 0; it < 8; ++it) {
    int idx = it * 256 + t;
    int r2 = idx >> 3, wi = (idx & 7) * 2;
    float4 v = *(const float4*)&T[((size_t)k1 * 256 + r2) * 64 + wq + wi];
    *(float4*)&tile[r2 * 18 + wi] = v;
  }
  if (t < 16) {
    float sn, cs; sincosf(SIGN * PI2F * (float)t / 16.f, &sn, &cs);
    tw16s[t] = make_float2(cs, sn);
  }
  __syncthreads();
  float2 twr[16];
  #pragma unroll
  for (int j = 0; j < 16; ++j) twr[j] = tw16s[j];

  // ---- phase A: thread (n2a = t>>4, w = t&15): radix-16 DFT over n1
  {
    const int n2a = t >> 4, w = t & 15;
    float2 d[16];
    #pragma unroll
    for (int n1 = 0; n1 < 16; ++n1)
      d[n1] = tile[(16 * n1 + n2a) * 18 + w];
    float2 y[16];
    #pragma unroll
    for (int k = 0; k < 16; ++k) {
      float2 a = d[0];
      #pragma unroll
      for (int n1 = 1; n1 < 16; ++n1) {
        float2 tv = twr[(n1 * k) & 15];
        a.x += d[n1].x * tv.x - d[n1].y * tv.y;
        a.y += d[n1].x * tv.y + d[n1].y * tv.x;
      }
      y[k] = a;
    }
    float sstep, cstep;                        // W256^{n2a*k}, incremental
    sincosf(SIGN * PI2F * (float)n2a / 256.f, &sstep, &cstep);
    float2 rot = make_float2(1.f, 0.f);
    #pragma unroll
    for (int k = 0; k < 16; ++k) {
      float2 a = y[k];
      y[k] = make_float2(a.x * rot.x - a.y * rot.y, a.x * rot.y + a.y * rot.x);
      float nrx = rot.x * cstep - rot.y * sstep;
      rot.y = rot.x * sstep + rot.y * cstep;
      rot.x = nrx;
    }
    __syncthreads();                           // all reads done
    #pragma unroll
    for (int k = 0; k < 16; ++k)
      tile[(n2a * 16 + k) * 18 + w] = y[k];
  }
  __syncthreads();                             // y visible

  // ---- phase B: thread (k1pb = t>>4, wB = t&15): radix-16 DFT over n2
  const int k1pb = t >> 4, wB = t & 15;
  float2 d[16];
  #pragma unroll
  for (int n2 = 0; n2 < 16; ++n2)
    d[n2] = tile[(n2 * 16 + k1pb) * 18 + wB];
  const float sc = SCALE ? (1.f / 32768.f) : 1.f;
  #pragma unroll
  for (int k2p = 0; k2p < 16; ++k2p) {
    float2 a = d[0];
    #pragma unroll
    for (int n2 = 1; n2 < 16; ++n2) {
      float2 tv = twr[(n2 * k2p) & 15];
      a.x += d[n2].x * tv.x - d[n2].y * tv.y;
      a.y += d[n2].x * tv.y + d[n2].y * tv.x;
    }
    int k2 = k1pb + 16 * k2p;
    size_t row = (size_t)(k1 + 128 * k2);
    X[row * 64 + wq + wB] = make_float2(a.x * sc, a.y * sc);
  }
}

// ---------------------------------------------------------------------------
// Pointwise A+/- fold, lin1 crelu, Q-fold (ifft64+lin2).
// ---------------------------------------------------------------------------
__global__ __launch_bounds__(256) void pw_lin(
    const float2* __restrict__ xh,
    const float2* __restrict__ Ap, const float2* __restrict__ Am,
    const float* __restrict__ l1W, const float* __restrict__ l1b,
    const float2* __restrict__ Qt, const float2* __restrict__ b2c,
    float2* __restrict__ u)
{
  __shared__ __align__(16) float2 tile[32][64];   // y, then z in place
  __shared__ __align__(16) float2 qt[64 * 64];    // Qt[w][j], 32KB
  const int t = threadIdx.x;
  const int lane = t & 63;
  const int wv = t >> 6;
  const size_t b0 = (size_t)blockIdx.x * 32;

  // stage Qt (32KB) via async DMA: 32 x 1KB instrs, 8 per wave
  #pragma unroll
  for (int s = 0; s < 8; ++s) {
    int instr = wv * 8 + s;
    gl2lds16((const char*)Qt + instr * 1024 + lane * 16,
             (const char*)qt + instr * 1024);
  }

  // phase 0: pointwise A+/- fold -> y
  for (int it = 0; it < 8; ++it) {
    int idx = it * 256 + t;
    int r = idx >> 6, w = idx & 63;
    float2 xv = xh[(b0 + r) * 64 + w];
    float2 Aa = (xv.x >= 0.f) ? Ap[w] : Am[w];
    float2 Ab = (xv.y >= 0.f) ? Ap[w] : Am[w];
    tile[r][w] = make_float2(xv.x * Aa.x - xv.y * Ab.y,
                             xv.x * Aa.y + xv.y * Ab.x);
  }
  __syncthreads();   // y visible to all waves; Qt DMA drained (vmcnt0)

  const int n = lane, rg = wv;   // wave rg owns tile rows [8rg, 8rg+8)

  // lin1: z[r][n] = crelu(sum_w y[r][w] * l1W[n][w] + b[n]); in place.
  {
    float2 acc[8] = {};
    const float* wrow = l1W + n * 64;
    float4 lwn = *(const float4*)wrow;             // rolling prefetch
    #pragma unroll 1
    for (int w2 = 0; w2 < 16; ++w2) {
      float4 lw = lwn;
      lwn = *(const float4*)(wrow + 4 * ((w2 + 1) & 15));
      int w = 4 * w2;
      #pragma unroll
      for (int r = 0; r < 8; ++r) {
        const float4* rowp = (const float4*)(&tile[rg * 8 + r][w]);
        float4 y01 = rowp[0];                      // broadcast b128
        float4 y23 = rowp[1];
        acc[r].x += y01.x * lw.x + y01.z * lw.y + y23.x * lw.z + y23.z * lw.w;
        acc[r].y += y01.y * lw.x + y01.w * lw.y + y23.y * lw.z + y23.w * lw.w;
      }
    }
    float bb = l1b[n];
    #pragma unroll
    for (int r = 0; r < 8; ++r) {
      float zr = acc[r].x + bb; zr = zr > 0.f ? zr : 0.f;
      float zi = acc[r].y;      zi = zi > 0.f ? zi : 0.f;
      tile[rg * 8 + r][n] = make_float2(zr, zi);   // same-wave rows only
    }
  }

  // Q-fold: u[r][j] = sum_w z[r][w] * Qt[w][j] + b2c[j]
  {
    const int j = lane;
    float2 acc[8] = {};
    #pragma unroll 1
    for (int w2 = 0; w2 < 16; ++w2) {
      int w = 4 * w2;
      float2 q0 = qt[(w + 0) * 64 + j];            // contiguous per-lane b64
      float2 q1 = qt[(w + 1) * 64 + j];
      float2 q2 = qt[(w + 2) * 64 + j];
      float2 q3 = qt[(w + 3) * 64 + j];
      #pragma unroll
      for (int r = 0; r < 8; ++r) {
        const float4* rowp = (const float4*)(&tile[rg * 8 + r][w]);
        float4 z01 = rowp[0];                      // broadcast b128
        float4 z23 = rowp[1];
        acc[r].x += z01.x * q0.x - z01.y * q0.y
                  + z01.z * q1.x - z01.w * q1.y
                  + z23.x * q2.x - z23.y * q2.y
                  + z23.z * q3.x - z23.w * q3.y;
        acc[r].y += z01.x * q0.y + z01.y * q0.x
                  + z01.z * q1.y + z01.w * q1.x
                  + z23.x * q2.y + z23.y * q2.x
                  + z23.z * q3.y + z23.w * q3.x;
      }
    }
    float2 bc = b2c[j];
    #pragma unroll
    for (int r = 0; r < 8; ++r)
      u[(b0 + rg * 8 + r) * 64 + j] = make_float2(acc[r].x + bc.x, acc[r].y + bc.y);
  }
}

// ---------------------------------------------------------------------------
// Final W_out GEMM; MODE 0 = real only, MODE 1 = interleaved (re,im).
// ---------------------------------------------------------------------------
template<int MODE>
__global__ __launch_bounds__(256) void final_out(
    const float2* __restrict__ v, const float* __restrict__ Wout,
    const float* __restrict__ bout, float* __restrict__ out)
{
  __shared__ __align__(16) float2 vt[32][64];
  const int t = threadIdx.x;
  const size_t b0 = (size_t)blockIdx.x * 32;
  for (int it = 0; it < 8; ++it) {
    int idx = it * 256 + t;
    int r = idx >> 6, w = idx & 63;
    vt[r][w] = v[(b0 + r) * 64 + w];
  }
  __syncthreads();
  const int f = t & 127, rg = t >> 7;
  const float* wrow = Wout + f * 64;
  float2 acc[16] = {};
  float2 wvn = *(const float2*)wrow;               // rolling prefetch
  #pragma unroll 1
  for (int j2 = 0; j2 < 32; ++j2) {
    float2 wc = wvn;
    wvn = *(const float2*)(wrow + 2 * ((j2 + 1) & 31));
    #pragma unroll
    for (int r = 0; r < 16; ++r) {
      float4 vv = *(const float4*)(&vt[rg * 16 + r][2 * j2]);  // broadcast b128
      acc[r].x += vv.x * wc.x + vv.z * wc.y;
      acc[r].y += vv.y * wc.x + vv.w * wc.y;
    }
  }
  float bb = bout[f];
  #pragma unroll
  for (int r = 0; r < 16; ++r) {
    size_t idx = (b0 + rg * 16 + r) * 128 + f;
    if (MODE == 0) out[idx] = acc[r].x + bb;
    else ((float2*)out)[idx] = make_float2(acc[r].x + bb, acc[r].y);
  }
}

// ---------------------------------------------------------------------------
extern "C" void kernel_launch(void* const* d_in, const int* in_sizes, int n_in,
                              void* d_out, int out_size, void* d_ws, size_t ws_size,
                              hipStream_t stream)
{
  (void)in_sizes; (void)n_in; (void)ws_size;
  const float* geom = (const float*)d_in[0];
  const float* Win  = (const float*)d_in[1];
  const float* bin  = (const float*)d_in[2];
  const float* Wh1  = (const float*)d_in[3];
  const float* bh1  = (const float*)d_in[4];
  const float* Wh2  = (const float*)d_in[5];
  const float* bh2  = (const float*)d_in[6];
  const float* w0   = (const float*)d_in[7];
  const float* w1   = (const float*)d_in[8];
  const float* l1W  = (const float*)d_in[9];
  const float* l1b  = (const float*)d_in[10];
  const float* l2W  = (const float*)d_in[11];
  const float* l2b  = (const float*)d_in[12];
  const float* Wout = (const float*)d_in[13];
  const float* bout = (const float*)d_in[14];

  char* ws = (char*)d_ws;
  const size_t MB = 1048576ull;
  unsigned short* geomb = (unsigned short*)(ws);
  unsigned short* x2b   = (unsigned short*)(ws);
  unsigned short* x1b   = (unsigned short*)(ws + 32 * MB);
  float2* S0  = (float2*)(ws + 40 * MB);
  float2* S1  = (float2*)(ws + 56 * MB);
  float2* Ap  = (float2*)(ws + 72 * MB);
  float2* Am  = (float2*)(ws + 72 * MB + 512);
  float2* b2c = (float2*)(ws + 72 * MB + 1024);
  float2* Qt  = (float2*)(ws + 72 * MB + 1536);
  unsigned short* Winb = (unsigned short*)(ws + 96 * MB);
  unsigned short* Wh1b = (unsigned short*)(ws + 97 * MB);
  unsigned short* Wh2b = (unsigned short*)(ws + 98 * MB);

  // fused conversions: geom (16384 blocks) + 3 weight arrays (1057 blocks)
  conv_all<<<17441, 256, 0, stream>>>(geom, Win, Wh1, Wh2,
                                      geomb, Winb, Wh1b, Wh2b);

  // GEMM1: [32768,512] x [1024,512]^T -> bf16 [32768,1024]; 256 x 4 blocks
  gemm_pipe<2, unsigned short><<<1024, 512, 0, stream>>>(
      geomb, Winb, bin, x1b, 1024, 512);
  // GEMM2: [32768,1024] x [512,1024]^T -> bf16 [32768,512]; 256 x 2 blocks
  gemm_pipe<1, unsigned short><<<512, 512, 0, stream>>>(
      x1b, Wh1b, bh1, x2b, 512, 1024);
  // GEMM3 + row-DFT fused: [32768,512] x [64,512]^T -> relu -> dft64 -> S0
  gemm3_dft<<<256, 256, 0, stream>>>(x2b, Wh2b, bh2, S0, 512);

  precompute<<<17, 256, 0, stream>>>(w0, w1, l2W, l2b, Ap, Am, Qt, b2c);
  fft_stage1<-1><<<512, 256, 0, stream>>>(S0, S1);
  fft_stage2<-1, false><<<512, 256, 0, stream>>>(S1, S0);
  pw_lin<<<1024, 256, 0, stream>>>(S0, Ap, Am, l1W, l1b, Qt, b2c, S1);
  fft_stage1<1><<<512, 256, 0, stream>>>(S1, S0);
  fft_stage2<1, true><<<512, 256, 0, stream>>>(S0, S1);
  if (out_size >= 8388608) {
    final_out<1><<<1024, 256, 0, stream>>>(S1, Wout, bout, (float*)d_out);
  } else {
    final_out<0><<<1024, 256, 0, stream>>>(S1, Wout, bout, (float*)d_out);
  }
}

// Round 13
// 405.940 us; speedup vs baseline: 1.0465x; 1.0177x over previous
//
#include <hip/hip_runtime.h>
#include <hip/hip_bf16.h>

// ---------------------------------------------------------------------------
// FieldPredictionNetwork. R17 (2nd submit — R12 bench was a broker timeout;
// kernel never ran; DMA-mapping/coverage/barrier audits clean). Budget says
// the 4 batch-FFT stages (~35-45us each, ~160us total) dominate; they are
// latency/occupancy-bound (2 blocks/CU, scalar tile loads, 3 serial phases;
// mem floor 5.3us, VALU floor 2.8us). Fix: (a) LINEAR LDS tiles (R13 mapping
// is lane-row-contiguous -> pad not needed) enabling global_load_lds DMA
// staging; (b) stage1 quarter-width grid 1024 (4 blk/CU), stage2 512-thread
// blocks; (c) k-output split across thread groups via template-constant
// twiddle indices (rule #20 safe), halving per-thread y[] registers.
// GEMMs + gemm3_dft + pw_lin + final_out frozen at R16 (413.1us measured).
// ---------------------------------------------------------------------------

#define PI2F 6.28318530717958647692f

typedef __attribute__((ext_vector_type(8))) short short8;
typedef __attribute__((ext_vector_type(4))) float f32x4;

__device__ __forceinline__ unsigned short f2bf(float f) {
  unsigned int u = __float_as_uint(f);
  u += 0x7fff + ((u >> 16) & 1);          // RN-even
  return (unsigned short)(u >> 16);
}
__device__ __forceinline__ unsigned int pack_bf16x2(float a, float b) {
  return (unsigned int)f2bf(a) | ((unsigned int)f2bf(b) << 16);
}

// async 16B global->LDS DMA; lds dest must be wave-uniform (HW adds lane*16)
__device__ __forceinline__ void gl2lds16(const void* gptr, const void* lptr) {
  __builtin_amdgcn_global_load_lds(
      (const __attribute__((address_space(1))) unsigned int*)(unsigned long long)gptr,
      (__attribute__((address_space(3))) unsigned int*)(unsigned int)(unsigned long long)lptr,
      16, 0, 0);
}

// 16-input DFT, 8 outputs [K0, K0+8): all twiddle indices compile-time.
template<int K0>
__device__ __forceinline__ void dft16part(const float2* d, const float2* twr,
                                          float2* y)
{
  #pragma unroll
  for (int kk = 0; kk < 8; ++kk) {
    float2 a = d[0];
    #pragma unroll
    for (int n1 = 1; n1 < 16; ++n1) {
      float2 tv = twr[(n1 * (K0 + kk)) & 15];
      a.x += d[n1].x * tv.x - d[n1].y * tv.y;
      a.y += d[n1].x * tv.y + d[n1].y * tv.x;
    }
    y[kk] = a;
  }
}

// ---------------------------------------------------------------------------
// Fused f32 -> bf16 pack: geom (16384 blocks) + Win + Wh1 + Wh2 in one launch
// ---------------------------------------------------------------------------
__global__ __launch_bounds__(256) void conv_all(
    const float* __restrict__ geom, const float* __restrict__ Win,
    const float* __restrict__ Wh1, const float* __restrict__ Wh2,
    unsigned short* __restrict__ dg, unsigned short* __restrict__ dw,
    unsigned short* __restrict__ d1, unsigned short* __restrict__ d2)
{
  int i = blockIdx.x * 256 + threadIdx.x;
  const float* s; unsigned short* d; int off;
  if (i < 4194304)      { s = geom; d = dg; off = i; }
  else if (i < 4325376) { s = Win;  d = dw; off = i - 4194304; }
  else if (i < 4456448) { s = Wh1;  d = d1; off = i - 4325376; }
  else if (i < 4464640) { s = Wh2;  d = d2; off = i - 4456448; }
  else return;
  float4 v = ((const float4*)s)[off];
  uint2 p;
  p.x = pack_bf16x2(v.x, v.y);
  p.y = pack_bf16x2(v.z, v.w);
  ((uint2*)d)[off] = p;
}

// ---------------------------------------------------------------------------
// R14 pipelined GEMM (frozen): C = relu(A @ Bw^T + bias). A [M,K], Bw [N,K]
// bf16. BM=128, BN=256, BK=64. 3-buffer LDS ring (144KB), counted vmcnt,
// 8 waves, ONE barrier per k-tile; reads+stage+MFMA merged.
// 1D grid, nwg = (M/128)*(N/256), nwg % 8 == 0 required (XCD swizzle).
// ---------------------------------------------------------------------------
template<int NBLOG, typename OUT>
__global__ __launch_bounds__(512, 1) void gemm_pipe(
    const unsigned short* __restrict__ A, const unsigned short* __restrict__ Bw,
    const float* __restrict__ bias, OUT* __restrict__ C, int N, int K)
{
  constexpr int BM = 128, BN = 256, BK = 64;
  constexpr int ASZ = BM * BK;            // 8192 elems = 16 KB
  constexpr int BSZ = BN * BK;            // 16384 elems = 32 KB
  constexpr int BUF = ASZ + BSZ;          // 48 KB
  __shared__ __align__(16) unsigned short lds[3 * BUF];   // 144 KB

  // T1: bijective XCD swizzle (nwg multiple of 8) -> contiguous chunk per XCD
  const int nwg = gridDim.x;
  const int cpx = nwg >> 3;
  const int orig = blockIdx.x;
  const int wg = (orig & 7) * cpx + (orig >> 3);
  const int mb = wg >> NBLOG;
  const int nb = wg & ((1 << NBLOG) - 1);
  const size_t m0 = (size_t)mb * BM;
  const size_t n0 = (size_t)nb * BN;

  const int tid = threadIdx.x;
  const int lane = tid & 63;
  const int wv = tid >> 6;
  const int q = lane >> 4, lr = lane & 15;
  const int x7 = lr & 7;
  const int wm = (wv >> 2) * 64;          // 2 M-positions
  const int wn = (wv & 3) * 64;           // 4 N-positions
  f32x4 acc[4][4] = {};

  // stage this wave's 6 DMA instrs for one k-tile into ring buffer r.
  auto STAGE = [&](int r, int kk) {
    unsigned short* dA = lds + r * BUF;
    #pragma unroll
    for (int u = 0; u < 6; ++u) {
      int e = wv * 6 + u;
      int isA = (e < 16) ? 1 : 0;
      int e2 = isA ? e : e - 16;
      int pc = e2 * 64 + lane;
      int row = pc >> 3, col = pc & 7;
      int lc = col ^ (row & 7);
      const unsigned short* src = isA ? A : Bw;
      size_t rb = isA ? m0 : n0;
      unsigned short* dst = dA + (isA ? 0 : ASZ) + e2 * 512;
      gl2lds16(src + (rb + row) * (size_t)K + kk + lc * 8, dst);
    }
  };

  const int nt = K / BK;                  // 8 or 16 here
  STAGE(0, 0);
  STAGE(1, BK);
  asm volatile("s_waitcnt vmcnt(6)" ::: "memory");
  __builtin_amdgcn_s_barrier();

  int r0 = 0;
  for (int t = 0; t < nt; ++t) {
    const unsigned short* sA = lds + r0 * BUF;
    const unsigned short* sB = sA + ASZ;
    const bool st = (t + 2) < nt;
    const int r2 = (r0 >= 1) ? (r0 - 1) : 2;    // (t+2)%3
    const int kk2 = (t + 2) * BK;

    short8 af[4][2], bfr[4][2];
    #pragma unroll
    for (int i = 0; i < 4; ++i)
      #pragma unroll
      for (int t2 = 0; t2 < 2; ++t2)
        af[i][t2] = *(const short8*)(sA + (wm + i * 16 + lr) * 64 + (((t2 << 2) | q) ^ x7) * 8);
    #pragma unroll
    for (int j = 0; j < 4; ++j)
      #pragma unroll
      for (int t2 = 0; t2 < 2; ++t2)
        bfr[j][t2] = *(const short8*)(sB + (wn + j * 16 + lr) * 64 + (((t2 << 2) | q) ^ x7) * 8);
    if (st) STAGE(r2, kk2);
    __builtin_amdgcn_s_setprio(1);
    #pragma unroll
    for (int i = 0; i < 4; ++i)
      #pragma unroll
      for (int j = 0; j < 4; ++j)
        #pragma unroll
        for (int t2 = 0; t2 < 2; ++t2)
          acc[i][j] = __builtin_amdgcn_mfma_f32_16x16x32_bf16(af[i][t2], bfr[j][t2], acc[i][j], 0, 0, 0);
    __builtin_amdgcn_s_setprio(0);

    asm volatile("s_waitcnt lgkmcnt(0)" ::: "memory");
    if (st) { asm volatile("s_waitcnt vmcnt(6)" ::: "memory"); }
    else    { asm volatile("s_waitcnt vmcnt(0)" ::: "memory"); }
    __builtin_amdgcn_s_barrier();
    r0 = (r0 + 1 >= 3) ? 0 : r0 + 1;
  }

  #pragma unroll
  for (int i = 0; i < 4; ++i)
    #pragma unroll
    for (int j = 0; j < 4; ++j) {
      size_t col = n0 + wn + j * 16 + lr;
      float bv = bias[col];
      #pragma unroll
      for (int r = 0; r < 4; ++r) {
        size_t row = m0 + wm + i * 16 + q * 4 + r;
        float v = acc[i][j][r] + bv;
        v = v > 0.f ? v : 0.f;
        if (sizeof(OUT) == 2) ((unsigned short*)C)[row * N + col] = f2bf(v);
        else                  ((float*)C)[row * N + col] = v;
      }
    }
}

// ---------------------------------------------------------------------------
// R16 fused GEMM3 + row-DFT (frozen): x3 = relu(x2 @ Wh2^T + bh2) -> LDS
// [128][68] -> 64-pt forward DFT along w -> S0 complex. 256 blocks.
// ---------------------------------------------------------------------------
__global__ __launch_bounds__(256) void gemm3_dft(
    const unsigned short* __restrict__ A, const unsigned short* __restrict__ Bw,
    const float* __restrict__ bias, float2* __restrict__ S0, int K)
{
  constexpr int BM = 128, BN = 64, BK = 64;
  __shared__ __align__(16) unsigned short lA[BM * BK];   // 16 KB
  __shared__ __align__(16) unsigned short lB[BN * BK];   // 8 KB
  __shared__ __align__(16) float xt[128][68];            // 34.8 KB
  __shared__ float2 tw[64];
  const int tid = threadIdx.x;
  const int lane = tid & 63;
  const int wv = tid >> 6;
  const int q = lane >> 4, lr = lane & 15;
  const int x7 = lr & 7;
  const int wm = (wv >> 1) * 64;          // 2 M-positions
  const int wn = (wv & 1) * 32;           // 2 N-positions
  const size_t m0 = (size_t)blockIdx.x * BM;
  f32x4 acc[4][2] = {};
  constexpr int A_PW = (BM * BK / 512) / 4;   // 4 instrs/wave
  constexpr int B_PW = (BN * BK / 512) / 4;   // 2 instrs/wave

  if (tid < 64) {
    float sn, cs; sincosf(-PI2F * (float)tid / 64.f, &sn, &cs);
    tw[tid] = make_float2(cs, sn);
  }

  for (int k0 = 0; k0 < K; k0 += BK) {
    __syncthreads();
    #pragma unroll
    for (int s = 0; s < A_PW; ++s) {
      int instr = wv * A_PW + s;
      int pc = instr * 64 + lane;
      int row = pc >> 3, col = pc & 7;
      int lc = col ^ (row & 7);
      gl2lds16(A + (m0 + row) * (size_t)K + k0 + lc * 8, lA + instr * 512);
    }
    #pragma unroll
    for (int s = 0; s < B_PW; ++s) {
      int instr = wv * B_PW + s;
      int pc = instr * 64 + lane;
      int row = pc >> 3, col = pc & 7;
      int lc = col ^ (row & 7);
      gl2lds16(Bw + (size_t)row * K + k0 + lc * 8, lB + instr * 512);
    }
    __syncthreads();
    #pragma unroll
    for (int t = 0; t < 2; ++t) {
      short8 af[4], bfr[2];
      #pragma unroll
      for (int i = 0; i < 4; ++i) {
        int r = wm + i * 16 + lr;
        af[i] = *(const short8*)(lA + r * 64 + (((t << 2) | q) ^ x7) * 8);
      }
      #pragma unroll
      for (int j = 0; j < 2; ++j) {
        int r = wn + j * 16 + lr;
        bfr[j] = *(const short8*)(lB + r * 64 + (((t << 2) | q) ^ x7) * 8);
      }
      #pragma unroll
      for (int i = 0; i < 4; ++i)
        #pragma unroll
        for (int j = 0; j < 2; ++j)
          acc[i][j] = __builtin_amdgcn_mfma_f32_16x16x32_bf16(af[i], bfr[j], acc[i][j], 0, 0, 0);
    }
  }

  // epilogue -> LDS (bias + relu), then in-block 64-pt DFT along w.
  __syncthreads();                         // all k-loop ds_reads retired
  #pragma unroll
  for (int i = 0; i < 4; ++i)
    #pragma unroll
    for (int j = 0; j < 2; ++j) {
      int col = wn + j * 16 + lr;
      float bv = bias[col];
      #pragma unroll
      for (int r = 0; r < 4; ++r) {
        int rowl = wm + i * 16 + q * 4 + r;
        float v = acc[i][j][r] + bv;
        xt[rowl][col] = v > 0.f ? v : 0.f;
      }
    }
  __syncthreads();                         // xt + tw visible

  const int k = tid & 63, rg = tid >> 6;   // rg owns rows [32rg, 32rg+32)
  #pragma unroll 1
  for (int half = 0; half < 2; ++half) {
    const int rb = rg * 32 + half * 16;
    float2 dacc[16] = {};
    #pragma unroll 1
    for (int w4 = 0; w4 < 16; ++w4) {
      int w = 4 * w4;
      int kw = k * w;
      float2 t0 = tw[kw & 63];
      float2 t1 = tw[(kw + k) & 63];
      float2 t2 = tw[(kw + 2 * k) & 63];
      float2 t3 = tw[(kw + 3 * k) & 63];
      #pragma unroll
      for (int r = 0; r < 16; ++r) {
        float4 xv = *(const float4*)(&xt[rb + r][w]);
        dacc[r].x += xv.x * t0.x + xv.y * t1.x + xv.z * t2.x + xv.w * t3.x;
        dacc[r].y += xv.x * t0.y + xv.y * t1.y + xv.z * t2.y + xv.w * t3.y;
      }
    }
    #pragma unroll
    for (int r = 0; r < 16; ++r)
      S0[(m0 + rb + r) * 64 + k] = dacc[r];
  }
}

// ---------------------------------------------------------------------------
// Precompute (parallel): block 0 -> Ap/Am/b2c; blocks 1..16 -> Qt (TRANSPOSED)
// ---------------------------------------------------------------------------
__global__ __launch_bounds__(256) void precompute(
    const float* __restrict__ w0, const float* __restrict__ w1,
    const float* __restrict__ l2W, const float* __restrict__ l2b,
    float2* __restrict__ Ap, float2* __restrict__ Am,
    float2* __restrict__ Qt, float2* __restrict__ b2c)
{
  const int t = threadIdx.x;
  const int blk = blockIdx.x;
  if (blk == 0) {
    if (t < 64) {
      float apx = 0, apy = 0, amx = 0, amy = 0;
      for (int m = 0; m < 32; ++m) {
        float s0 = w0[m * 64 + t];
        float cf = w1[m * 64 + t] * s0;
        float sn, cs; sincosf(PI2F * (float)m / 32.f, &sn, &cs);
        if (s0 > 0.f)      { apx += cs * cf; apy += sn * cf; }
        else if (s0 < 0.f) { amx += cs * cf; amy += sn * cf; }
      }
      Ap[t] = make_float2(apx, apy);
      Am[t] = make_float2(amx, amy);
      float bx = 0, by = 0;
      for (int k = 0; k < 64; ++k) {
        float sn, cs; sincosf(PI2F * (float)((t * k) & 63) / 64.f, &sn, &cs);
        float lb = l2b[k] * (1.f / 64.f);
        bx += cs * lb; by += sn * lb;
      }
      b2c[t] = make_float2(bx, by);
    }
  } else {
    int e = (blk - 1) * 256 + t;
    int j = e >> 6, w = e & 63;
    float qx = 0, qy = 0;
    for (int k = 0; k < 64; ++k) {
      float sn, cs; sincosf(PI2F * (float)((j * k) & 63) / 64.f, &sn, &cs);
      float lw = l2W[k * 64 + w] * (1.f / 64.f);
      qx += cs * lw; qy += sn * lw;
    }
    Qt[w * 64 + j] = make_float2(qx, qy);   // transposed store
  }
}

// ---------------------------------------------------------------------------
// Batch-axis FFT stage 1 (R17): 128-pt DFT over b1 as radix-16 x radix-8 +
// inter-stage twiddle. Quarter-width tiles [128][16] LINEAR, DMA staging,
// grid 1024 (4 blk/CU). Phase A: 128 (n2a,w) pairs x 2 k-groups
// (template-constant twiddles). Phase B: full 256 threads, radix-8.
// ---------------------------------------------------------------------------
template<int SIGN>
__global__ __launch_bounds__(256) void fft_stage1(
    const float2* __restrict__ Xin, float2* __restrict__ T)
{
  __shared__ __align__(16) float2 tile[128 * 16];   // 16 KB linear
  __shared__ float2 tw16s[16];
  const int blk = blockIdx.x;
  const int b2 = blk >> 2, wh = (blk & 3) * 16;
  const int t = threadIdx.x;
  const int lane = t & 63, wvv = t >> 6;
  // DMA: 16 instrs (4/wave); instr covers 8 rows; lane l -> row instr*8+(l>>3)
  #pragma unroll
  for (int s = 0; s < 4; ++s) {
    int instr = wvv * 4 + s;
    int b1 = instr * 8 + (lane >> 3);
    int wi = (lane & 7) * 2;
    gl2lds16(Xin + ((size_t)(b1 * 256 + b2)) * 64 + wh + wi,
             (const char*)tile + instr * 1024);
  }
  if (t < 16) {
    float sn, cs; sincosf(SIGN * PI2F * (float)t / 16.f, &sn, &cs);
    tw16s[t] = make_float2(cs, sn);
  }
  __syncthreads();                        // drains DMA (vmcnt0) + tw visible
  float2 twr[16];
  #pragma unroll
  for (int j = 0; j < 16; ++j) twr[j] = tw16s[j];

  // ---- phase A: (ko = t>>7 in {0,1}; n2a = (t>>4)&7; w = t&15)
  const int ko = t >> 7;
  const int n2a = (t >> 4) & 7, w = t & 15;
  float2 y[8];
  {
    float2 d[16];
    #pragma unroll
    for (int n1 = 0; n1 < 16; ++n1)
      d[n1] = tile[(8 * n1 + n2a) * 16 + w];
    if (ko == 0) dft16part<0>(d, twr, y);
    else         dft16part<8>(d, twr, y);
    float sstep, cstep;                   // W128^{n2a*k}, incremental
    sincosf(SIGN * PI2F * (float)n2a / 128.f, &sstep, &cstep);
    float s0, c0;                         // start at k = 8*ko
    sincosf(SIGN * PI2F * (float)(n2a * (ko * 8)) / 128.f, &s0, &c0);
    float2 rot = make_float2(c0, s0);
    #pragma unroll
    for (int kk = 0; kk < 8; ++kk) {
      float2 a = y[kk];
      y[kk] = make_float2(a.x * rot.x - a.y * rot.y, a.x * rot.y + a.y * rot.x);
      float nrx = rot.x * cstep - rot.y * sstep;
      rot.y = rot.x * sstep + rot.y * cstep;
      rot.x = nrx;
    }
  }
  __syncthreads();                        // all phase-A reads done
  #pragma unroll
  for (int kk = 0; kk < 8; ++kk)
    tile[(n2a * 16 + ko * 8 + kk) * 16 + w] = y[kk];
  __syncthreads();                        // y visible

  // ---- phase B: k1p = t>>4 (16), wB = t&15; radix-8 over n2
  const int k1p = t >> 4, wB = t & 15;
  float2 d2[8];
  #pragma unroll
  for (int n2 = 0; n2 < 8; ++n2)
    d2[n2] = tile[(n2 * 16 + k1p) * 16 + wB];
  float2 acc[8];
  #pragma unroll
  for (int k2p = 0; k2p < 8; ++k2p) {
    float2 a = d2[0];
    #pragma unroll
    for (int n2 = 1; n2 < 8; ++n2) {
      float2 tv = twr[(2 * n2 * k2p) & 15];   // W8^{n2 k2p}
      a.x += d2[n2].x * tv.x - d2[n2].y * tv.y;
      a.y += d2[n2].x * tv.y + d2[n2].y * tv.x;
    }
    acc[k2p] = a;
  }
  float sstep, cstep;
  sincosf(SIGN * PI2F * (float)(16 * b2) / 32768.f, &sstep, &cstep);
  float sb, cb;
  sincosf(SIGN * PI2F * (float)(b2 * k1p) / 32768.f, &sb, &cb);
  float2 rot = make_float2(cb, sb);
  #pragma unroll
  for (int k2p = 0; k2p < 8; ++k2p) {
    int k1 = k1p + 16 * k2p;
    float2 a = acc[k2p];
    T[((size_t)k1 * 256 + b2) * 64 + wh + wB] =
        make_float2(a.x * rot.x - a.y * rot.y, a.x * rot.y + a.y * rot.x);
    float nrx = rot.x * cstep - rot.y * sstep;
    rot.y = rot.x * sstep + rot.y * cstep;
    rot.x = nrx;
  }
}

// ---------------------------------------------------------------------------
// Batch-axis FFT stage 2 (R17): 256-pt DFT as radix-16 x radix-16.
// [256][16] LINEAR + DMA, 512 threads (16 waves/CU), grid 512.
// Phases A and B each split their 16 outputs across the 2 thread halves.
// ---------------------------------------------------------------------------
template<int SIGN, bool SCALE>
__global__ __launch_bounds__(512) void fft_stage2(
    const float2* __restrict__ T, float2* __restrict__ X)
{
  __shared__ __align__(16) float2 tile[256 * 16];   // 32 KB linear
  __shared__ float2 tw16s[16];
  const int blk = blockIdx.x;
  const int k1 = blk >> 2, wq = (blk & 3) * 16;
  const int t = threadIdx.x;
  const int lane = t & 63, wvv = t >> 6;
  // DMA: 32 instrs (4/wave x 8 waves); instr covers 8 rows.
  #pragma unroll
  for (int s = 0; s < 4; ++s) {
    int instr = wvv * 4 + s;
    int r2 = instr * 8 + (lane >> 3);
    int wi = (lane & 7) * 2;
    gl2lds16(T + ((size_t)k1 * 256 + r2) * 64 + wq + wi,
             (const char*)tile + instr * 1024);
  }
  if (t < 16) {
    float sn, cs; sincosf(SIGN * PI2F * (float)t / 16.f, &sn, &cs);
    tw16s[t] = make_float2(cs, sn);
  }
  __syncthreads();
  float2 twr[16];
  #pragma unroll
  for (int j = 0; j < 16; ++j) twr[j] = tw16s[j];

  // ---- phase A: (ko = t>>8; n2a = (t>>4)&15; w = t&15)
  const int ko = t >> 8;
  const int n2a = (t >> 4) & 15, w = t & 15;
  float2 y[8];
  {
    float2 d[16];
    #pragma unroll
    for (int n1 = 0; n1 < 16; ++n1)
      d[n1] = tile[(16 * n1 + n2a) * 16 + w];
    if (ko == 0) dft16part<0>(d, twr, y);
    else         dft16part<8>(d, twr, y);
    float sstep, cstep;                   // W256^{n2a*k}, incremental
    sincosf(SIGN * PI2F * (float)n2a / 256.f, &sstep, &cstep);
    float s0, c0;                         // start at k = 8*ko
    sincosf(SIGN * PI2F * (float)(n2a * (ko * 8)) / 256.f, &s0, &c0);
    float2 rot = make_float2(c0, s0);
    #pragma unroll
    for (int kk = 0; kk < 8; ++kk) {
      float2 a = y[kk];
      y[kk] = make_float2(a.x * rot.x - a.y * rot.y, a.x * rot.y + a.y * rot.x);
      float nrx = rot.x * cstep - rot.y * sstep;
      rot.y = rot.x * sstep + rot.y * cstep;
      rot.x = nrx;
    }
  }
  __syncthreads();                        // all phase-A reads done
  #pragma unroll
  for (int kk = 0; kk < 8; ++kk)
    tile[(n2a * 16 + ko * 8 + kk) * 16 + w] = y[kk];
  __syncthreads();                        // y visible

  // ---- phase B: (kb = t>>8; k1pb = (t>>4)&15; wB = t&15)
  const int kb = t >> 8;
  const int k1pb = (t >> 4) & 15, wB = t & 15;
  float2 d2[16];
  #pragma unroll
  for (int n2 = 0; n2 < 16; ++n2)
    d2[n2] = tile[(n2 * 16 + k1pb) * 16 + wB];
  float2 acc[8];
  if (kb == 0) dft16part<0>(d2, twr, acc);
  else         dft16part<8>(d2, twr, acc);
  const float sc = SCALE ? (1.f / 32768.f) : 1.f;
  #pragma unroll
  for (int kk = 0; kk < 8; ++kk) {
    int k2p = kb * 8 + kk;
    int k2 = k1pb + 16 * k2p;
    size_t row = (size_t)(k1 + 128 * k2);
    X[row * 64 + wq + wB] = make_float2(acc[kk].x * sc, acc[kk].y * sc);
  }
}

// ---------------------------------------------------------------------------
// Pointwise A+/- fold, lin1 crelu, Q-fold (ifft64+lin2). Frozen at R16.
// ---------------------------------------------------------------------------
__global__ __launch_bounds__(256) void pw_lin(
    const float2* __restrict__ xh,
    const float2* __restrict__ Ap, const float2* __restrict__ Am,
    const float* __restrict__ l1W, const float* __restrict__ l1b,
    const float2* __restrict__ Qt, const float2* __restrict__ b2c,
    float2* __restrict__ u)
{
  __shared__ __align__(16) float2 tile[32][64];   // y, then z in place
  __shared__ __align__(16) float2 qt[64 * 64];    // Qt[w][j], 32KB
  const int t = threadIdx.x;
  const int lane = t & 63;
  const int wv = t >> 6;
  const size_t b0 = (size_t)blockIdx.x * 32;

  // stage Qt (32KB) via async DMA: 32 x 1KB instrs, 8 per wave
  #pragma unroll
  for (int s = 0; s < 8; ++s) {
    int instr = wv * 8 + s;
    gl2lds16((const char*)Qt + instr * 1024 + lane * 16,
             (const char*)qt + instr * 1024);
  }

  // phase 0: pointwise A+/- fold -> y
  for (int it = 0; it < 8; ++it) {
    int idx = it * 256 + t;
    int r = idx >> 6, w = idx & 63;
    float2 xv = xh[(b0 + r) * 64 + w];
    float2 Aa = (xv.x >= 0.f) ? Ap[w] : Am[w];
    float2 Ab = (xv.y >= 0.f) ? Ap[w] : Am[w];
    tile[r][w] = make_float2(xv.x * Aa.x - xv.y * Ab.y,
                             xv.x * Aa.y + xv.y * Ab.x);
  }
  __syncthreads();   // y visible to all waves; Qt DMA drained (vmcnt0)

  const int n = lane, rg = wv;   // wave rg owns tile rows [8rg, 8rg+8)

  // lin1: z[r][n] = crelu(sum_w y[r][w] * l1W[n][w] + b[n]); in place.
  {
    float2 acc[8] = {};
    const float* wrow = l1W + n * 64;
    float4 lwn = *(const float4*)wrow;             // rolling prefetch
    #pragma unroll 1
    for (int w2 = 0; w2 < 16; ++w2) {
      float4 lw = lwn;
      lwn = *(const float4*)(wrow + 4 * ((w2 + 1) & 15));
      int w = 4 * w2;
      #pragma unroll
      for (int r = 0; r < 8; ++r) {
        const float4* rowp = (const float4*)(&tile[rg * 8 + r][w]);
        float4 y01 = rowp[0];                      // broadcast b128
        float4 y23 = rowp[1];
        acc[r].x += y01.x * lw.x + y01.z * lw.y + y23.x * lw.z + y23.z * lw.w;
        acc[r].y += y01.y * lw.x + y01.w * lw.y + y23.y * lw.z + y23.w * lw.w;
      }
    }
    float bb = l1b[n];
    #pragma unroll
    for (int r = 0; r < 8; ++r) {
      float zr = acc[r].x + bb; zr = zr > 0.f ? zr : 0.f;
      float zi = acc[r].y;      zi = zi > 0.f ? zi : 0.f;
      tile[rg * 8 + r][n] = make_float2(zr, zi);   // same-wave rows only
    }
  }

  // Q-fold: u[r][j] = sum_w z[r][w] * Qt[w][j] + b2c[j]
  {
    const int j = lane;
    float2 acc[8] = {};
    #pragma unroll 1
    for (int w2 = 0; w2 < 16; ++w2) {
      int w = 4 * w2;
      float2 q0 = qt[(w + 0) * 64 + j];            // contiguous per-lane b64
      float2 q1 = qt[(w + 1) * 64 + j];
      float2 q2 = qt[(w + 2) * 64 + j];
      float2 q3 = qt[(w + 3) * 64 + j];
      #pragma unroll
      for (int r = 0; r < 8; ++r) {
        const float4* rowp = (const float4*)(&tile[rg * 8 + r][w]);
        float4 z01 = rowp[0];                      // broadcast b128
        float4 z23 = rowp[1];
        acc[r].x += z01.x * q0.x - z01.y * q0.y
                  + z01.z * q1.x - z01.w * q1.y
                  + z23.x * q2.x - z23.y * q2.y
                  + z23.z * q3.x - z23.w * q3.y;
        acc[r].y += z01.x * q0.y + z01.y * q0.x
                  + z01.z * q1.y + z01.w * q1.x
                  + z23.x * q2.y + z23.y * q2.x
                  + z23.z * q3.y + z23.w * q3.x;
      }
    }
    float2 bc = b2c[j];
    #pragma unroll
    for (int r = 0; r < 8; ++r)
      u[(b0 + rg * 8 + r) * 64 + j] = make_float2(acc[r].x + bc.x, acc[r].y + bc.y);
  }
}

// ---------------------------------------------------------------------------
// Final W_out GEMM; MODE 0 = real only, MODE 1 = interleaved (re,im). Frozen.
// ---------------------------------------------------------------------------
template<int MODE>
__global__ __launch_bounds__(256) void final_out(
    const float2* __restrict__ v, const float* __restrict__ Wout,
    const float* __restrict__ bout, float* __restrict__ out)
{
  __shared__ __align__(16) float2 vt[32][64];
  const int t = threadIdx.x;
  const size_t b0 = (size_t)blockIdx.x * 32;
  for (int it = 0; it < 8; ++it) {
    int idx = it * 256 + t;
    int r = idx >> 6, w = idx & 63;
    vt[r][w] = v[(b0 + r) * 64 + w];
  }
  __syncthreads();
  const int f = t & 127, rg = t >> 7;
  const float* wrow = Wout + f * 64;
  float2 acc[16] = {};
  float2 wvn = *(const float2*)wrow;               // rolling prefetch
  #pragma unroll 1
  for (int j2 = 0; j2 < 32; ++j2) {
    float2 wc = wvn;
    wvn = *(const float2*)(wrow + 2 * ((j2 + 1) & 31));
    #pragma unroll
    for (int r = 0; r < 16; ++r) {
      float4 vv = *(const float4*)(&vt[rg * 16 + r][2 * j2]);  // broadcast b128
      acc[r].x += vv.x * wc.x + vv.z * wc.y;
      acc[r].y += vv.y * wc.x + vv.w * wc.y;
    }
  }
  float bb = bout[f];
  #pragma unroll
  for (int r = 0; r < 16; ++r) {
    size_t idx = (b0 + rg * 16 + r) * 128 + f;
    if (MODE == 0) out[idx] = acc[r].x + bb;
    else ((float2*)out)[idx] = make_float2(acc[r].x + bb, acc[r].y);
  }
}

// ---------------------------------------------------------------------------
extern "C" void kernel_launch(void* const* d_in, const int* in_sizes, int n_in,
                              void* d_out, int out_size, void* d_ws, size_t ws_size,
                              hipStream_t stream)
{
  (void)in_sizes; (void)n_in; (void)ws_size;
  const float* geom = (const float*)d_in[0];
  const float* Win  = (const float*)d_in[1];
  const float* bin  = (const float*)d_in[2];
  const float* Wh1  = (const float*)d_in[3];
  const float* bh1  = (const float*)d_in[4];
  const float* Wh2  = (const float*)d_in[5];
  const float* bh2  = (const float*)d_in[6];
  const float* w0   = (const float*)d_in[7];
  const float* w1   = (const float*)d_in[8];
  const float* l1W  = (const float*)d_in[9];
  const float* l1b  = (const float*)d_in[10];
  const float* l2W  = (const float*)d_in[11];
  const float* l2b  = (const float*)d_in[12];
  const float* Wout = (const float*)d_in[13];
  const float* bout = (const float*)d_in[14];

  char* ws = (char*)d_ws;
  const size_t MB = 1048576ull;
  unsigned short* geomb = (unsigned short*)(ws);
  unsigned short* x2b   = (unsigned short*)(ws);
  unsigned short* x1b   = (unsigned short*)(ws + 32 * MB);
  float2* S0  = (float2*)(ws + 40 * MB);
  float2* S1  = (float2*)(ws + 56 * MB);
  float2* Ap  = (float2*)(ws + 72 * MB);
  float2* Am  = (float2*)(ws + 72 * MB + 512);
  float2* b2c = (float2*)(ws + 72 * MB + 1024);
  float2* Qt  = (float2*)(ws + 72 * MB + 1536);
  unsigned short* Winb = (unsigned short*)(ws + 96 * MB);
  unsigned short* Wh1b = (unsigned short*)(ws + 97 * MB);
  unsigned short* Wh2b = (unsigned short*)(ws + 98 * MB);

  // fused conversions: geom (16384 blocks) + 3 weight arrays (1057 blocks)
  conv_all<<<17441, 256, 0, stream>>>(geom, Win, Wh1, Wh2,
                                      geomb, Winb, Wh1b, Wh2b);

  // GEMM1: [32768,512] x [1024,512]^T -> bf16 [32768,1024]; 256 x 4 blocks
  gemm_pipe<2, unsigned short><<<1024, 512, 0, stream>>>(
      geomb, Winb, bin, x1b, 1024, 512);
  // GEMM2: [32768,1024] x [512,1024]^T -> bf16 [32768,512]; 256 x 2 blocks
  gemm_pipe<1, unsigned short><<<512, 512, 0, stream>>>(
      x1b, Wh1b, bh1, x2b, 512, 1024);
  // GEMM3 + row-DFT fused: [32768,512] x [64,512]^T -> relu -> dft64 -> S0
  gemm3_dft<<<256, 256, 0, stream>>>(x2b, Wh2b, bh2, S0, 512);

  precompute<<<17, 256, 0, stream>>>(w0, w1, l2W, l2b, Ap, Am, Qt, b2c);
  fft_stage1<-1><<<1024, 256, 0, stream>>>(S0, S1);
  fft_stage2<-1, false><<<512, 512, 0, stream>>>(S1, S0);
  pw_lin<<<1024, 256, 0, stream>>>(S0, Ap, Am, l1W, l1b, Qt, b2c, S1);
  fft_stage1<1><<<1024, 256, 0, stream>>>(S1, S0);
  fft_stage2<1, true><<<512, 512, 0, stream>>>(S0, S1);
  if (out_size >= 8388608) {
    final_out<1><<<1024, 256, 0, stream>>>(S1, Wout, bout, (float*)d_out);
  } else {
    final_out<0><<<1024, 256, 0, stream>>>(S1, Wout, bout, (float*)d_out);
  }
}